// Round 17
// baseline (469.403 us; speedup 1.0000x reference)
//
#include <hip/hip_runtime.h>

// ---------------------------------------------------------------------------
// TransformerBlock on MI355X (gfx950), bf16 MFMA internal compute.
// B=4 T=2048 C=1024 H=16 D=64 FF=4096. All fp32 I/O; bf16 internally.
//
// R16: revert attention to R11-exact (R15's merged softmax spilled to
// scratch: FETCH +34MB, WRITE +26MB, 103->119us).
// gemm_bt (proj/FF2): B operand read DIRECTLY from global into regs
// (no Bs LDS) -> LDS traffic/step 48KB->24KB, LDS 8KB, 4 blocks/CU.
// gemm_big (QKV/FF1) unchanged from R13.
// ---------------------------------------------------------------------------

#define DEVI __device__ __forceinline__

typedef float  f32x4  __attribute__((ext_vector_type(4)));
typedef float  f32x16 __attribute__((ext_vector_type(16)));
typedef __bf16 bf16x8 __attribute__((ext_vector_type(8)));
typedef short  s16x8  __attribute__((ext_vector_type(8)));
typedef unsigned int u32x4 __attribute__((ext_vector_type(4)));
typedef unsigned short u16;

DEVI u16 f2bf(float f) {            // native RNE fp32->bf16
    return __builtin_bit_cast(u16, (__bf16)f);
}

DEVI float bf2f(u16 u) {
    unsigned v = (unsigned)u << 16;
    return __builtin_bit_cast(float, v);
}

DEVI unsigned pk2(float lo, float hi2) {    // {bf16(lo), bf16(hi2)} dword
    return (unsigned)f2bf(lo) | ((unsigned)f2bf(hi2) << 16);
}

DEVI void gload_lds16(const void* g, void* l) {
    __builtin_amdgcn_global_load_lds(
        (__attribute__((address_space(1))) void*)(g),
        (__attribute__((address_space(3))) void*)(l), 16, 0, 0);
}

DEVI f32x4 mfma16(s16x8 a, s16x8 b, f32x4 c) {
    return __builtin_amdgcn_mfma_f32_16x16x32_bf16(
        __builtin_bit_cast(bf16x8, a), __builtin_bit_cast(bf16x8, b), c, 0, 0, 0);
}

DEVI f32x16 mfma32(s16x8 a, s16x8 b, f32x16 c) {
    return __builtin_amdgcn_mfma_f32_32x32x16_bf16(
        __builtin_bit_cast(bf16x8, a), __builtin_bit_cast(bf16x8, b), c, 0, 0, 0);
}

// ---------------------------------------------------------------------------
// Tiled transpose + fp32->bf16: dst[n][k] = src[k][n].  64x64 tile, 256 thr.
// ---------------------------------------------------------------------------
__global__ __launch_bounds__(256) void transpose_cvt(
    const float* __restrict__ src, u16* __restrict__ dst,
    int K, int N, long srcStride, long dstStride)
{
    __shared__ float t[64][65];
    src += (long)blockIdx.z * srcStride;
    dst += (long)blockIdx.z * dstStride;
    int k0 = blockIdx.x * 64, n0 = blockIdx.y * 64;
    int tx = threadIdx.x & 63, ty = threadIdx.x >> 6;
#pragma unroll
    for (int i = 0; i < 16; ++i) {
        int r = ty * 16 + i;
        t[r][tx] = src[(long)(k0 + r) * N + n0 + tx];
    }
    __syncthreads();
#pragma unroll
    for (int i = 0; i < 16; ++i) {
        int r = ty * 16 + i;
        dst[(long)(n0 + r) * K + k0 + tx] = f2bf(t[tx][r]);
    }
}

// ---------------------------------------------------------------------------
// LayerNorm row (C=1024) -> bf16.  1 row / block, 256 threads, float4 loads.
// ---------------------------------------------------------------------------
__global__ __launch_bounds__(256) void ln_bf16(
    const float* __restrict__ x, const float* __restrict__ g,
    const float* __restrict__ b, u16* __restrict__ out)
{
    int row = blockIdx.x, tid = threadIdx.x;
    const float4 v = ((const float4*)(x + (long)row * 1024))[tid];
    float s = v.x + v.y + v.z + v.w;
    float q = v.x * v.x + v.y * v.y + v.z * v.z + v.w * v.w;
#pragma unroll
    for (int m = 1; m < 64; m <<= 1) { s += __shfl_xor(s, m); q += __shfl_xor(q, m); }
    __shared__ float red[8];
    int lane = tid & 63, w = tid >> 6;
    if (lane == 0) { red[w] = s; red[w + 4] = q; }
    __syncthreads();
    s = red[0] + red[1] + red[2] + red[3];
    q = red[4] + red[5] + red[6] + red[7];
    float mu  = s * (1.0f / 1024.0f);
    float var = q * (1.0f / 1024.0f) - mu * mu;
    float rs  = rsqrtf(var + 1e-5f);
    float4 gv = ((const float4*)g)[tid];
    float4 bv = ((const float4*)b)[tid];
    ushort4 o;
    o.x = f2bf((v.x - mu) * rs * gv.x + bv.x);
    o.y = f2bf((v.y - mu) * rs * gv.y + bv.y);
    o.z = f2bf((v.z - mu) * rs * gv.z + bv.z);
    o.w = f2bf((v.w - mu) * rs * gv.w + bv.w);
    ((ushort4*)(out + (long)row * 1024))[tid] = o;
}

// ---------------------------------------------------------------------------
// gemm_big: C[M,N] = A[M,K] * Bt[N,K]^T.  256x128 tile, BK=32, 512 thr
// (8 waves 4Mx2N).  Chunk-swizzled LDS (row&3).  24KB LDS, 4 blocks/CU.
// EPI: 0 = QKV scatter (V transposed), 2 = relu(+bias) -> bf16.
// ---------------------------------------------------------------------------
template <int EPI>
__global__ __launch_bounds__(512, 4) void gemm_big(
    const u16* __restrict__ A, const u16* __restrict__ Bt,
    int M, int N, int K,
    u16* __restrict__ outB, const float* __restrict__ bias,
    u16* __restrict__ qd, u16* __restrict__ kd, u16* __restrict__ vd)
{
    __shared__ alignas(16) u16 As[256 * 32];
    __shared__ alignas(16) u16 Bs[128 * 32];
    int tid = threadIdx.x;
    int lane = tid & 63, w = tid >> 6;
    int wm = w >> 1, wn = w & 1;
    int l15 = lane & 15, l4 = lane >> 4;
    long m0 = (long)blockIdx.x * 256, n0 = (long)blockIdx.y * 128;
    const u16* Ag = A + m0 * K;
    const u16* Bg = Bt + n0 * K;
    int srow_l = lane >> 2;                        // 0..15
    int schunk = ((lane & 3) ^ (srow_l & 3)) * 8;  // inverse-swizzled source
    int rchunk = (l4 ^ (l15 & 3)) * 8;             // swizzled read chunk

    f32x4 acc[4][4] = {};

    for (int kt = 0; kt < K; kt += 32) {
        gload_lds16(Ag + (long)(w * 32 + srow_l) * K + kt + schunk,
                    &As[(w * 32) * 32]);
        gload_lds16(Ag + (long)(w * 32 + 16 + srow_l) * K + kt + schunk,
                    &As[(w * 32 + 16) * 32]);
        gload_lds16(Bg + (long)(w * 16 + srow_l) * K + kt + schunk,
                    &Bs[(w * 16) * 32]);
        __syncthreads();
        s16x8 a[4], b[4];
#pragma unroll
        for (int m = 0; m < 4; ++m)
            a[m] = *(const s16x8*)&As[(wm * 64 + m * 16 + l15) * 32 + rchunk];
#pragma unroll
        for (int n = 0; n < 4; ++n)
            b[n] = *(const s16x8*)&Bs[(wn * 64 + n * 16 + l15) * 32 + rchunk];
#pragma unroll
        for (int m = 0; m < 4; ++m)
#pragma unroll
            for (int n = 0; n < 4; ++n)
                acc[m][n] = mfma16(a[m], b[n], acc[m][n]);
        __syncthreads();
    }

    long mbase = m0 + wm * 64;
    long nbase = n0 + wn * 64;
#pragma unroll
    for (int m = 0; m < 4; ++m)
#pragma unroll
        for (int n = 0; n < 4; ++n)
#pragma unroll
            for (int r = 0; r < 4; ++r) {
                long row = mbase + m * 16 + l4 * 4 + r;
                long col = nbase + n * 16 + l15;
                float val = acc[m][n][r];
                if constexpr (EPI == 0) {
                    int c = (int)col;
                    int which = c >> 10, hh = (c >> 6) & 15, dd = c & 63;
                    int bb = (int)(row >> 11), tt = (int)(row & 2047);
                    if (which == 2) {
                        vd[((long)(bb * 16 + hh) * 64 + dd) * 2048 + tt] = f2bf(val);
                    } else {
                        u16* dst = which == 0 ? qd : kd;
                        dst[((long)(bb * 16 + hh) * 2048 + tt) * 64 + dd] = f2bf(val);
                    }
                } else {
                    float t2 = val + bias[col];
                    outB[row * N + col] = f2bf(t2 > 0.f ? t2 : 0.f);
                }
            }
}

// ---------------------------------------------------------------------------
// GEMM 128x128 for proj / FF2.  A via LDS (chunk-swizzled); B DIRECT from
// global into regs (no LDS) -> half the LDS port traffic.  8KB LDS, 4/CU.
// EPI 1 = +bias+resid -> fp32.
// ---------------------------------------------------------------------------
template <int EPI>
__global__ __launch_bounds__(256, 4) void gemm_bt(
    const u16* __restrict__ A, const u16* __restrict__ Bt,
    int M, int N, int K,
    float* __restrict__ outF, u16* __restrict__ outB,
    const float* __restrict__ bias, const float* __restrict__ resid,
    u16* __restrict__ qd, u16* __restrict__ kd, u16* __restrict__ vd)
{
    __shared__ alignas(16) u16 As[128 * 32];
    int tid = threadIdx.x;
    int lane = tid & 63, w = tid >> 6;
    int wm = w & 1, wn = w >> 1;
    int l15 = lane & 15, l4 = lane >> 4;
    long m0 = (long)blockIdx.x * 128, n0 = (long)blockIdx.y * 128;
    const u16* Ag = A + m0 * K;
    const u16* Bg = Bt + n0 * K;
    int scol = ((lane & 3) ^ ((lane >> 2) & 3)) * 8;   // inverse-swizzled src
    int srow0 = (w * 2 + 0) * 16 + (lane >> 2);
    int srow1 = (w * 2 + 1) * 16 + (lane >> 2);
    int rchunk = (l4 ^ (l15 & 3)) * 8;                 // swizzled read chunk
    // per-wave B row pointers (global, K-contiguous)
    const u16* Bw = Bg + (long)(wn * 64 + l15) * K + l4 * 8;

    f32x4 acc[4][4] = {};

    for (int kt = 0; kt < K; kt += 32) {
        // issue B global loads for this step (drained by the barrier's vmcnt)
        s16x8 b[4];
#pragma unroll
        for (int n = 0; n < 4; ++n)
            b[n] = *(const s16x8*)&Bw[(long)(n * 16) * K + kt];
        gload_lds16(Ag + (long)srow0 * K + kt + scol, &As[(w * 2 + 0) * 512]);
        gload_lds16(Ag + (long)srow1 * K + kt + scol, &As[(w * 2 + 1) * 512]);
        __syncthreads();
        s16x8 a[4];
#pragma unroll
        for (int m = 0; m < 4; ++m)
            a[m] = *(const s16x8*)&As[(wm * 64 + m * 16 + l15) * 32 + rchunk];
#pragma unroll
        for (int m = 0; m < 4; ++m)
#pragma unroll
            for (int n = 0; n < 4; ++n)
                acc[m][n] = mfma16(a[m], b[n], acc[m][n]);
        __syncthreads();
    }

    long mbase = m0 + wm * 64;
    long nbase = n0 + wn * 64;
#pragma unroll
    for (int m = 0; m < 4; ++m)
#pragma unroll
        for (int n = 0; n < 4; ++n)
#pragma unroll
            for (int r = 0; r < 4; ++r) {
                long row = mbase + m * 16 + l4 * 4 + r;
                long col = nbase + n * 16 + l15;
                float val = acc[m][n][r];
                if constexpr (EPI == 1) {
                    outF[row * N + col] = val + bias[col] + resid[row * N + col];
                }
            }
}

// ---------------------------------------------------------------------------
// Causal flash attention, split-K partials (R11-exact).
// Block p = (qt=p, s=0) then (qt=15-p, s=1); 17 tiles/block, 4 blocks/CU.
// ---------------------------------------------------------------------------
__global__ __launch_bounds__(256, 4) void attn_split(
    const u16* __restrict__ Q, const u16* __restrict__ K,
    const u16* __restrict__ Vt,
    u16* __restrict__ Op0, u16* __restrict__ Op1, float* __restrict__ ML)
{
    constexpr int PAD = 72;
    constexpr float SC2 = 0.125f * 1.44269504088896f;   // scale * log2(e)
    constexpr float THR = 11.5416f;                     // 8 * log2(e)
    __shared__ alignas(16) u16 Ks[2][64 * PAD];
    __shared__ alignas(16) u16 Vts[2][64 * PAD];
    __shared__ alignas(16) float xbuf[4][32];           // per-wave bounce
    int tid = threadIdx.x, lane = tid & 63, w = tid >> 6;
    int l31 = lane & 31, hi = lane >> 5;
    bool h = (hi != 0);
    int p = blockIdx.x, hh = blockIdx.y, bb = blockIdx.z;
    const long hbase = ((long)(bb * 16 + hh)) * 2048 * 64;
    const long rb = ((long)(bb * 16 + hh)) * 2048;      // partial row base

    int srow[2], scol8[2];
#pragma unroll
    for (int i = 0; i < 2; ++i) {
        int c = tid + 256 * i;
        srow[i] = c >> 3;
        scol8[i] = (c & 7) * 8;
    }

#pragma unroll 1
    for (int ph = 0; ph < 2; ++ph) {
        int qt  = ph == 0 ? p : 15 - p;
        int kt0 = ph == 0 ? 0 : (qt + 1);
        int kt1 = qt + 1 + ph * (qt + 1);   // ph0: qt+1, ph1: 2qt+2
        int ntl = kt1 - kt0;
        int q0w = qt * 128 + w * 32;
        int qv = q0w + l31;                 // this lane's q row

        s16x8 bq[4];
#pragma unroll
        for (int c = 0; c < 4; ++c)
            bq[c] = *(const s16x8*)&Q[hbase + (long)(q0w + l31) * 64 + c * 16 + hi * 8];

        f32x16 o0 = {}, o1 = {};            // O'[q=crow][d=l31 | 32+l31]
        float mrow = -1e30f, lrow = 0.f;

        s16x8 kr[2], vr[2];
        {
            const u16* Kg = K + hbase + (long)kt0 * 64 * 64;
            const u16* Vg = Vt + hbase + (long)kt0 * 64;
#pragma unroll
            for (int i = 0; i < 2; ++i) {
                s16x8 k0 = *(const s16x8*)&Kg[srow[i] * 64 + scol8[i]];
                s16x8 v0 = *(const s16x8*)&Vg[(long)srow[i] * 2048 + scol8[i]];
                *(s16x8*)&Ks[0][srow[i] * PAD + scol8[i]]  = k0;
                *(s16x8*)&Vts[0][srow[i] * PAD + scol8[i]] = v0;
            }
            if (ntl > 1) {
                const u16* Kg1 = K + hbase + (long)(kt0 + 1) * 64 * 64;
                const u16* Vg1 = Vt + hbase + (long)(kt0 + 1) * 64;
#pragma unroll
                for (int i = 0; i < 2; ++i) {
                    kr[i] = *(const s16x8*)&Kg1[srow[i] * 64 + scol8[i]];
                    vr[i] = *(const s16x8*)&Vg1[(long)srow[i] * 2048 + scol8[i]];
                }
            }
        }
        __syncthreads();

#pragma unroll 1
        for (int j = 0; j < ntl; ++j) {
            int kt = kt0 + j;
            int cur = j & 1;
            if (j + 1 < ntl) {
#pragma unroll
                for (int i = 0; i < 2; ++i) {
                    *(s16x8*)&Ks[cur ^ 1][srow[i] * PAD + scol8[i]]  = kr[i];
                    *(s16x8*)&Vts[cur ^ 1][srow[i] * PAD + scol8[i]] = vr[i];
                }
            }
            if (j + 2 < ntl) {
                const u16* Kg = K + hbase + (long)(kt + 2) * 64 * 64;
                const u16* Vg = Vt + hbase + (long)(kt + 2) * 64;
#pragma unroll
                for (int i = 0; i < 2; ++i) {
                    kr[i] = *(const s16x8*)&Kg[srow[i] * 64 + scol8[i]];
                    vr[i] = *(const s16x8*)&Vg[(long)srow[i] * 2048 + scol8[i]];
                }
            }

#pragma unroll
            for (int k2 = 0; k2 < 2; ++k2) {
                int kbase = kt * 64 + k2 * 32;
                if (kbase <= q0w + 31) {    // else fully masked for this wave
                    f32x16 s = {};
                    __builtin_amdgcn_s_setprio(1);
#pragma unroll
                    for (int c = 0; c < 4; ++c) {
                        s16x8 ak = *(const s16x8*)&Ks[cur][(k2 * 32 + l31) * PAD + c * 16 + hi * 8];
                        s = mfma32(ak, bq[c], s);
                    }
                    __builtin_amdgcn_s_setprio(0);

                    // causal mask in RAW domain (diag-straddling tiles only)
                    if (kbase + 31 > q0w) {
                        int d = qv - (kbase + 4 * hi);  // pat > d -> masked
#pragma unroll
                        for (int r = 0; r < 16; ++r) {
                            int pat = (r & 3) + 8 * (r >> 2);
                            if (pat > d) s[r] = -3.0e38f;
                        }
                    }

                    // raw max tree, then single scale mul
                    float t8[8], t4[4];
#pragma unroll
                    for (int r = 0; r < 8; ++r) t8[r] = fmaxf(s[r], s[r + 8]);
#pragma unroll
                    for (int r = 0; r < 4; ++r) t4[r] = fmaxf(t8[r], t8[r + 4]);
                    float pm = fmaxf(fmaxf(t4[0], t4[2]), fmaxf(t4[1], t4[3]));
                    pm *= SC2;
                    pm = fmaxf(pm, __shfl_xor(pm, 32));

                    int allok = __all(pm - mrow <= THR);
                    float ef = 1.f;
                    if (!allok) {
                        float mn = fmaxf(mrow, pm);
                        ef = exp2f(mrow - mn);
                        mrow = mn;
                    }
                    // fused scale+shift exp2
#pragma unroll
                    for (int r = 0; r < 16; ++r) s[r] = exp2f(fmaf(s[r], SC2, -mrow));
                    float a8[8], a4[4];
#pragma unroll
                    for (int r = 0; r < 8; ++r) a8[r] = s[r] + s[r + 8];
#pragma unroll
                    for (int r = 0; r < 4; ++r) a4[r] = a8[r] + a8[r + 4];
                    float rsum = (a4[0] + a4[1]) + (a4[2] + a4[3]);
                    rsum += __shfl_xor(rsum, 32);

                    if (!allok) {
                        lrow = lrow * ef + rsum;
                        xbuf[w][l31] = ef;
#pragma unroll
                        for (int rr = 0; rr < 4; ++rr) {
                            f32x4 efv = *(const f32x4*)&xbuf[w][rr * 8 + hi * 4];
#pragma unroll
                            for (int j2 = 0; j2 < 4; ++j2) {
                                o0[rr * 4 + j2] *= efv[j2];
                                o1[rr * 4 + j2] *= efv[j2];
                            }
                        }
                    } else {
                        lrow += rsum;
                    }

                    unsigned c0 = pk2(s[0],  s[1]),  c1 = pk2(s[2],  s[3]);
                    unsigned c2 = pk2(s[4],  s[5]),  c3 = pk2(s[6],  s[7]);
                    unsigned c4 = pk2(s[8],  s[9]),  c5 = pk2(s[10], s[11]);
                    unsigned c6 = pk2(s[12], s[13]), c7 = pk2(s[14], s[15]);
                    unsigned x0 = __shfl_xor((int)c0, 32), x1 = __shfl_xor((int)c1, 32);
                    unsigned x2 = __shfl_xor((int)c2, 32), x3 = __shfl_xor((int)c3, 32);
                    unsigned x4 = __shfl_xor((int)c4, 32), x5 = __shfl_xor((int)c5, 32);
                    unsigned x6 = __shfl_xor((int)c6, 32), x7 = __shfl_xor((int)c7, 32);
                    u32x4 w0 = { h ? x2 : c0, h ? x3 : c1, h ? c2 : x0, h ? c3 : x1 };
                    u32x4 w1 = { h ? x6 : c4, h ? x7 : c5, h ? c6 : x4, h ? c7 : x5 };
                    s16x8 pa0 = __builtin_bit_cast(s16x8, w0);
                    s16x8 pa1 = __builtin_bit_cast(s16x8, w1);

                    __builtin_amdgcn_s_setprio(1);
#pragma unroll
                    for (int ks = 0; ks < 2; ++ks) {
                        s16x8 pa = ks ? pa1 : pa0;
                        s16x8 bv0 = *(const s16x8*)&Vts[cur][(l31) * PAD + k2 * 32 + ks * 16 + hi * 8];
                        s16x8 bv1 = *(const s16x8*)&Vts[cur][(32 + l31) * PAD + k2 * 32 + ks * 16 + hi * 8];
                        o0 = mfma32(pa, bv0, o0);
                        o1 = mfma32(pa, bv1, o1);
                    }
                    __builtin_amdgcn_s_setprio(0);
                }
            }
            __syncthreads();
        }

        // ---- partial epilogue: unnormalized O', m, l ----
        u16* Ops = ph ? Op1 : Op0;
#pragma unroll
        for (int r = 0; r < 16; ++r) {
            int t = q0w + ((r & 3) + 8 * (r >> 2)) + 4 * hi;
            long ro = (rb + t) * 64;
            Ops[ro + l31]      = f2bf(o0[r]);
            Ops[ro + 32 + l31] = f2bf(o1[r]);
        }
        if (hi == 0) {
            long mrow_i = rb + q0w + l31;
            ML[ph * 262144 + mrow_i]          = mrow;
            ML[ph * 262144 + 131072 + mrow_i] = lrow;
        }
        __syncthreads();   // protect LDS before next phase's prologue writes
    }
}

// ---------------------------------------------------------------------------
// Split-K combine: O = (w1*O1' + w2*O2') / (w1*l1 + w2*l2), w_s = 2^(m_s-mm).
// ---------------------------------------------------------------------------
__global__ __launch_bounds__(256) void attn_combine(
    const u16* __restrict__ Op0, const u16* __restrict__ Op1,
    const float* __restrict__ ML, u16* __restrict__ O)
{
    int tid = threadIdx.x;
    long row = (long)blockIdx.x * 16 + (tid >> 4);      // 0..131071
    int d0 = (tid & 15) * 4;
    float m1 = ML[row],          l1 = ML[131072 + row];
    float m2 = ML[262144 + row], l2 = ML[393216 + row];
    float mm = fmaxf(m1, m2);
    float w1 = exp2f(m1 - mm), w2 = exp2f(m2 - mm);
    float inv = 1.0f / (w1 * l1 + w2 * l2);
    ushort4 a = *(const ushort4*)&Op0[row * 64 + d0];
    ushort4 b = *(const ushort4*)&Op1[row * 64 + d0];
    ushort4 o;
    o.x = f2bf((w1 * bf2f(a.x) + w2 * bf2f(b.x)) * inv);
    o.y = f2bf((w1 * bf2f(a.y) + w2 * bf2f(b.y)) * inv);
    o.z = f2bf((w1 * bf2f(a.z) + w2 * bf2f(b.z)) * inv);
    o.w = f2bf((w1 * bf2f(a.w) + w2 * bf2f(b.w)) * inv);
    int bb = (int)(row >> 15), hh2 = (int)((row >> 11) & 15), t = (int)(row & 2047);
    *(ushort4*)&O[((long)(bb * 2048 + t)) * 1024 + hh2 * 64 + d0] = o;
}

// ---------------------------------------------------------------------------
extern "C" void kernel_launch(void* const* d_in, const int* in_sizes, int n_in,
                              void* d_out, int out_size, void* d_ws, size_t ws_size,
                              hipStream_t stream)
{
    const float* x      = (const float*)d_in[0];
    const float* wq     = (const float*)d_in[1];
    const float* wk     = (const float*)d_in[2];
    const float* wv     = (const float*)d_in[3];
    const float* w_proj = (const float*)d_in[4];
    const float* b_proj = (const float*)d_in[5];
    const float* w1     = (const float*)d_in[6];
    const float* b1     = (const float*)d_in[7];
    const float* w2     = (const float*)d_in[8];
    const float* b2     = (const float*)d_in[9];
    const float* ln1_g  = (const float*)d_in[10];
    const float* ln1_b  = (const float*)d_in[11];
    const float* ln2_g  = (const float*)d_in[12];
    const float* ln2_b  = (const float*)d_in[13];

    char* ws = (char*)d_ws;
    u16*   WQKVt = (u16*)(ws + 0);           // 3072x1024 bf16
    u16*   WPt   = (u16*)(ws + 6291456);     // 1024x1024
    u16*   W1t   = (u16*)(ws + 8388608);     // 4096x1024
    u16*   W2t   = (u16*)(ws + 16777216);    // 1024x4096
    u16*   H     = (u16*)(ws + 25165824);    // 8192x1024 (h, then h2)
    float* ML    = (float*)(ws + 25165824);  // overlaps H (dead during attn)
    u16*   Qb    = (u16*)(ws + 41943040);    // [B,H,T,D]
    u16*   Kb    = (u16*)(ws + 58720256);    // [B,H,T,D]
    u16*   Vb    = (u16*)(ws + 75497472);    // [B,H,D,T]  (transposed)
    u16*   Ob    = (u16*)(ws + 92274688);    // [B,T,C]
    u16*   FF    = (u16*)(ws + 41943040);    // 8192x4096, overlaps Q..O
    float* X1    = (float*)(ws + 109051904); // 8192x1024 fp32
    u16*   Op0   = (u16*)(ws + 109051904);   // split partials overlap X1
    u16*   Op1   = (u16*)(ws + 109051904 + 16777216);
    float* out   = (float*)d_out;

    transpose_cvt<<<dim3(16, 1, 16), 256, 0, stream>>>(wq, WQKVt,           1024, 64, 65536, 65536);
    transpose_cvt<<<dim3(16, 1, 16), 256, 0, stream>>>(wk, WQKVt + 1048576, 1024, 64, 65536, 65536);
    transpose_cvt<<<dim3(16, 1, 16), 256, 0, stream>>>(wv, WQKVt + 2097152, 1024, 64, 65536, 65536);
    transpose_cvt<<<dim3(16, 16, 1), 256, 0, stream>>>(w_proj, WPt, 1024, 1024, 0, 0);
    transpose_cvt<<<dim3(16, 64, 1), 256, 0, stream>>>(w1, W1t, 1024, 4096, 0, 0);
    transpose_cvt<<<dim3(64, 16, 1), 256, 0, stream>>>(w2, W2t, 4096, 1024, 0, 0);

    ln_bf16<<<8192, 256, 0, stream>>>(x, ln1_g, ln1_b, H);

    gemm_big<0><<<dim3(32, 24), 512, 0, stream>>>(H, WQKVt, 8192, 3072, 1024,
        nullptr, nullptr, Qb, Kb, Vb);

    attn_split<<<dim3(16, 16, 4), 256, 0, stream>>>(Qb, Kb, Vb, Op0, Op1, ML);
    attn_combine<<<8192, 256, 0, stream>>>(Op0, Op1, ML, Ob);

    gemm_bt<1><<<dim3(64, 8), 256, 0, stream>>>(Ob, WPt, 8192, 1024, 1024,
        X1, nullptr, b_proj, x, nullptr, nullptr, nullptr);

    ln_bf16<<<8192, 256, 0, stream>>>(X1, ln2_g, ln2_b, H);

    gemm_big<2><<<dim3(32, 32), 512, 0, stream>>>(H, W1t, 8192, 4096, 1024,
        FF, b1, nullptr, nullptr, nullptr);

    gemm_bt<1><<<dim3(64, 8), 256, 0, stream>>>(FF, W2t, 8192, 1024, 4096,
        out, nullptr, b2, X1, nullptr, nullptr, nullptr);
}

// Round 18
// 441.979 us; speedup vs baseline: 1.0620x; 1.0620x over previous
//
#include <hip/hip_runtime.h>

// ---------------------------------------------------------------------------
// TransformerBlock on MI355X (gfx950), bf16 MFMA internal compute.
// B=4 T=2048 C=1024 H=16 D=64 FF=4096. All fp32 I/O; bf16 internally.
//
// R17: revert gemm_bt to R13-exact (R16's direct-B exposed global latency:
// 104->151us; conflicts halved though -> counter tracks LDS reads, not
// critical path).  Single new arm: FF2 -> gemm_big (256x128) WITHOUT the
// XCD remap -- the R14 confound isolated.  Staged bytes 1GB -> 768MB.
// ---------------------------------------------------------------------------

#define DEVI __device__ __forceinline__

typedef float  f32x4  __attribute__((ext_vector_type(4)));
typedef float  f32x16 __attribute__((ext_vector_type(16)));
typedef __bf16 bf16x8 __attribute__((ext_vector_type(8)));
typedef short  s16x8  __attribute__((ext_vector_type(8)));
typedef unsigned int u32x4 __attribute__((ext_vector_type(4)));
typedef unsigned short u16;

DEVI u16 f2bf(float f) {            // native RNE fp32->bf16
    return __builtin_bit_cast(u16, (__bf16)f);
}

DEVI float bf2f(u16 u) {
    unsigned v = (unsigned)u << 16;
    return __builtin_bit_cast(float, v);
}

DEVI unsigned pk2(float lo, float hi2) {    // {bf16(lo), bf16(hi2)} dword
    return (unsigned)f2bf(lo) | ((unsigned)f2bf(hi2) << 16);
}

DEVI void gload_lds16(const void* g, void* l) {
    __builtin_amdgcn_global_load_lds(
        (__attribute__((address_space(1))) void*)(g),
        (__attribute__((address_space(3))) void*)(l), 16, 0, 0);
}

DEVI f32x4 mfma16(s16x8 a, s16x8 b, f32x4 c) {
    return __builtin_amdgcn_mfma_f32_16x16x32_bf16(
        __builtin_bit_cast(bf16x8, a), __builtin_bit_cast(bf16x8, b), c, 0, 0, 0);
}

DEVI f32x16 mfma32(s16x8 a, s16x8 b, f32x16 c) {
    return __builtin_amdgcn_mfma_f32_32x32x16_bf16(
        __builtin_bit_cast(bf16x8, a), __builtin_bit_cast(bf16x8, b), c, 0, 0, 0);
}

// ---------------------------------------------------------------------------
// Tiled transpose + fp32->bf16: dst[n][k] = src[k][n].  64x64 tile, 256 thr.
// ---------------------------------------------------------------------------
__global__ __launch_bounds__(256) void transpose_cvt(
    const float* __restrict__ src, u16* __restrict__ dst,
    int K, int N, long srcStride, long dstStride)
{
    __shared__ float t[64][65];
    src += (long)blockIdx.z * srcStride;
    dst += (long)blockIdx.z * dstStride;
    int k0 = blockIdx.x * 64, n0 = blockIdx.y * 64;
    int tx = threadIdx.x & 63, ty = threadIdx.x >> 6;
#pragma unroll
    for (int i = 0; i < 16; ++i) {
        int r = ty * 16 + i;
        t[r][tx] = src[(long)(k0 + r) * N + n0 + tx];
    }
    __syncthreads();
#pragma unroll
    for (int i = 0; i < 16; ++i) {
        int r = ty * 16 + i;
        dst[(long)(n0 + r) * K + k0 + tx] = f2bf(t[tx][r]);
    }
}

// ---------------------------------------------------------------------------
// LayerNorm row (C=1024) -> bf16.  1 row / block, 256 threads, float4 loads.
// ---------------------------------------------------------------------------
__global__ __launch_bounds__(256) void ln_bf16(
    const float* __restrict__ x, const float* __restrict__ g,
    const float* __restrict__ b, u16* __restrict__ out)
{
    int row = blockIdx.x, tid = threadIdx.x;
    const float4 v = ((const float4*)(x + (long)row * 1024))[tid];
    float s = v.x + v.y + v.z + v.w;
    float q = v.x * v.x + v.y * v.y + v.z * v.z + v.w * v.w;
#pragma unroll
    for (int m = 1; m < 64; m <<= 1) { s += __shfl_xor(s, m); q += __shfl_xor(q, m); }
    __shared__ float red[8];
    int lane = tid & 63, w = tid >> 6;
    if (lane == 0) { red[w] = s; red[w + 4] = q; }
    __syncthreads();
    s = red[0] + red[1] + red[2] + red[3];
    q = red[4] + red[5] + red[6] + red[7];
    float mu  = s * (1.0f / 1024.0f);
    float var = q * (1.0f / 1024.0f) - mu * mu;
    float rs  = rsqrtf(var + 1e-5f);
    float4 gv = ((const float4*)g)[tid];
    float4 bv = ((const float4*)b)[tid];
    ushort4 o;
    o.x = f2bf((v.x - mu) * rs * gv.x + bv.x);
    o.y = f2bf((v.y - mu) * rs * gv.y + bv.y);
    o.z = f2bf((v.z - mu) * rs * gv.z + bv.z);
    o.w = f2bf((v.w - mu) * rs * gv.w + bv.w);
    ((ushort4*)(out + (long)row * 1024))[tid] = o;
}

// ---------------------------------------------------------------------------
// gemm_big: C[M,N] = A[M,K] * Bt[N,K]^T.  256x128 tile, BK=32, 512 thr
// (8 waves 4Mx2N).  Chunk-swizzled LDS (row&3).  24KB LDS, 4 blocks/CU.
// EPI: 0 = QKV scatter (V transposed), 1 = +bias+resid -> fp32,
//      2 = relu(+bias) -> bf16.
// ---------------------------------------------------------------------------
template <int EPI>
__global__ __launch_bounds__(512, 4) void gemm_big(
    const u16* __restrict__ A, const u16* __restrict__ Bt,
    int M, int N, int K,
    float* __restrict__ outF, u16* __restrict__ outB,
    const float* __restrict__ bias, const float* __restrict__ resid,
    u16* __restrict__ qd, u16* __restrict__ kd, u16* __restrict__ vd)
{
    __shared__ alignas(16) u16 As[256 * 32];
    __shared__ alignas(16) u16 Bs[128 * 32];
    int tid = threadIdx.x;
    int lane = tid & 63, w = tid >> 6;
    int wm = w >> 1, wn = w & 1;
    int l15 = lane & 15, l4 = lane >> 4;
    long m0 = (long)blockIdx.x * 256, n0 = (long)blockIdx.y * 128;
    const u16* Ag = A + m0 * K;
    const u16* Bg = Bt + n0 * K;
    int srow_l = lane >> 2;                        // 0..15
    int schunk = ((lane & 3) ^ (srow_l & 3)) * 8;  // inverse-swizzled source
    int rchunk = (l4 ^ (l15 & 3)) * 8;             // swizzled read chunk

    f32x4 acc[4][4] = {};

    for (int kt = 0; kt < K; kt += 32) {
        gload_lds16(Ag + (long)(w * 32 + srow_l) * K + kt + schunk,
                    &As[(w * 32) * 32]);
        gload_lds16(Ag + (long)(w * 32 + 16 + srow_l) * K + kt + schunk,
                    &As[(w * 32 + 16) * 32]);
        gload_lds16(Bg + (long)(w * 16 + srow_l) * K + kt + schunk,
                    &Bs[(w * 16) * 32]);
        __syncthreads();
        s16x8 a[4], b[4];
#pragma unroll
        for (int m = 0; m < 4; ++m)
            a[m] = *(const s16x8*)&As[(wm * 64 + m * 16 + l15) * 32 + rchunk];
#pragma unroll
        for (int n = 0; n < 4; ++n)
            b[n] = *(const s16x8*)&Bs[(wn * 64 + n * 16 + l15) * 32 + rchunk];
#pragma unroll
        for (int m = 0; m < 4; ++m)
#pragma unroll
            for (int n = 0; n < 4; ++n)
                acc[m][n] = mfma16(a[m], b[n], acc[m][n]);
        __syncthreads();
    }

    long mbase = m0 + wm * 64;
    long nbase = n0 + wn * 64;
#pragma unroll
    for (int m = 0; m < 4; ++m)
#pragma unroll
        for (int n = 0; n < 4; ++n)
#pragma unroll
            for (int r = 0; r < 4; ++r) {
                long row = mbase + m * 16 + l4 * 4 + r;
                long col = nbase + n * 16 + l15;
                float val = acc[m][n][r];
                if constexpr (EPI == 0) {
                    int c = (int)col;
                    int which = c >> 10, hh = (c >> 6) & 15, dd = c & 63;
                    int bb = (int)(row >> 11), tt = (int)(row & 2047);
                    if (which == 2) {
                        vd[((long)(bb * 16 + hh) * 64 + dd) * 2048 + tt] = f2bf(val);
                    } else {
                        u16* dst = which == 0 ? qd : kd;
                        dst[((long)(bb * 16 + hh) * 2048 + tt) * 64 + dd] = f2bf(val);
                    }
                } else if constexpr (EPI == 1) {
                    outF[row * N + col] = val + bias[col] + resid[row * N + col];
                } else {
                    float t2 = val + bias[col];
                    outB[row * N + col] = f2bf(t2 > 0.f ? t2 : 0.f);
                }
            }
}

// ---------------------------------------------------------------------------
// GEMM 128x128 (m97 structure, R13-exact) for proj.  Chunk-swizzled LDS.
// EPI 1 = +bias+resid -> fp32.
// ---------------------------------------------------------------------------
template <int EPI>
__global__ __launch_bounds__(256, 3) void gemm_bt(
    const u16* __restrict__ A, const u16* __restrict__ Bt,
    int M, int N, int K,
    float* __restrict__ outF, u16* __restrict__ outB,
    const float* __restrict__ bias, const float* __restrict__ resid,
    u16* __restrict__ qd, u16* __restrict__ kd, u16* __restrict__ vd)
{
    __shared__ alignas(16) u16 As[128 * 32];
    __shared__ alignas(16) u16 Bs[128 * 32];
    int tid = threadIdx.x;
    int lane = tid & 63, w = tid >> 6;
    int wm = w & 1, wn = w >> 1;
    int l15 = lane & 15, l4 = lane >> 4;
    long m0 = (long)blockIdx.x * 128, n0 = (long)blockIdx.y * 128;
    const u16* Ag = A + m0 * K;
    const u16* Bg = Bt + n0 * K;
    int scol = ((lane & 3) ^ ((lane >> 2) & 3)) * 8;   // inverse-swizzled src
    int srow0 = (w * 2 + 0) * 16 + (lane >> 2);
    int srow1 = (w * 2 + 1) * 16 + (lane >> 2);
    int rchunk = (l4 ^ (l15 & 3)) * 8;                 // swizzled read chunk

    f32x4 acc[4][4] = {};

    for (int kt = 0; kt < K; kt += 32) {
        gload_lds16(Ag + (long)srow0 * K + kt + scol, &As[(w * 2 + 0) * 512]);
        gload_lds16(Ag + (long)srow1 * K + kt + scol, &As[(w * 2 + 1) * 512]);
        gload_lds16(Bg + (long)srow0 * K + kt + scol, &Bs[(w * 2 + 0) * 512]);
        gload_lds16(Bg + (long)srow1 * K + kt + scol, &Bs[(w * 2 + 1) * 512]);
        __syncthreads();
        s16x8 a[4], b[4];
#pragma unroll
        for (int m = 0; m < 4; ++m)
            a[m] = *(const s16x8*)&As[(wm * 64 + m * 16 + l15) * 32 + rchunk];
#pragma unroll
        for (int n = 0; n < 4; ++n)
            b[n] = *(const s16x8*)&Bs[(wn * 64 + n * 16 + l15) * 32 + rchunk];
#pragma unroll
        for (int m = 0; m < 4; ++m)
#pragma unroll
            for (int n = 0; n < 4; ++n)
                acc[m][n] = mfma16(a[m], b[n], acc[m][n]);
        __syncthreads();
    }

    long mbase = m0 + wm * 64;
    long nbase = n0 + wn * 64;
#pragma unroll
    for (int m = 0; m < 4; ++m)
#pragma unroll
        for (int n = 0; n < 4; ++n)
#pragma unroll
            for (int r = 0; r < 4; ++r) {
                long row = mbase + m * 16 + l4 * 4 + r;
                long col = nbase + n * 16 + l15;
                float val = acc[m][n][r];
                if constexpr (EPI == 1) {
                    outF[row * N + col] = val + bias[col] + resid[row * N + col];
                }
            }
}

// ---------------------------------------------------------------------------
// Causal flash attention, split-K partials (R11-exact).
// Block p = (qt=p, s=0) then (qt=15-p, s=1); 17 tiles/block, 4 blocks/CU.
// ---------------------------------------------------------------------------
__global__ __launch_bounds__(256, 4) void attn_split(
    const u16* __restrict__ Q, const u16* __restrict__ K,
    const u16* __restrict__ Vt,
    u16* __restrict__ Op0, u16* __restrict__ Op1, float* __restrict__ ML)
{
    constexpr int PAD = 72;
    constexpr float SC2 = 0.125f * 1.44269504088896f;   // scale * log2(e)
    constexpr float THR = 11.5416f;                     // 8 * log2(e)
    __shared__ alignas(16) u16 Ks[2][64 * PAD];
    __shared__ alignas(16) u16 Vts[2][64 * PAD];
    __shared__ alignas(16) float xbuf[4][32];           // per-wave bounce
    int tid = threadIdx.x, lane = tid & 63, w = tid >> 6;
    int l31 = lane & 31, hi = lane >> 5;
    bool h = (hi != 0);
    int p = blockIdx.x, hh = blockIdx.y, bb = blockIdx.z;
    const long hbase = ((long)(bb * 16 + hh)) * 2048 * 64;
    const long rb = ((long)(bb * 16 + hh)) * 2048;      // partial row base

    int srow[2], scol8[2];
#pragma unroll
    for (int i = 0; i < 2; ++i) {
        int c = tid + 256 * i;
        srow[i] = c >> 3;
        scol8[i] = (c & 7) * 8;
    }

#pragma unroll 1
    for (int ph = 0; ph < 2; ++ph) {
        int qt  = ph == 0 ? p : 15 - p;
        int kt0 = ph == 0 ? 0 : (qt + 1);
        int kt1 = qt + 1 + ph * (qt + 1);   // ph0: qt+1, ph1: 2qt+2
        int ntl = kt1 - kt0;
        int q0w = qt * 128 + w * 32;
        int qv = q0w + l31;                 // this lane's q row

        s16x8 bq[4];
#pragma unroll
        for (int c = 0; c < 4; ++c)
            bq[c] = *(const s16x8*)&Q[hbase + (long)(q0w + l31) * 64 + c * 16 + hi * 8];

        f32x16 o0 = {}, o1 = {};            // O'[q=crow][d=l31 | 32+l31]
        float mrow = -1e30f, lrow = 0.f;

        s16x8 kr[2], vr[2];
        {
            const u16* Kg = K + hbase + (long)kt0 * 64 * 64;
            const u16* Vg = Vt + hbase + (long)kt0 * 64;
#pragma unroll
            for (int i = 0; i < 2; ++i) {
                s16x8 k0 = *(const s16x8*)&Kg[srow[i] * 64 + scol8[i]];
                s16x8 v0 = *(const s16x8*)&Vg[(long)srow[i] * 2048 + scol8[i]];
                *(s16x8*)&Ks[0][srow[i] * PAD + scol8[i]]  = k0;
                *(s16x8*)&Vts[0][srow[i] * PAD + scol8[i]] = v0;
            }
            if (ntl > 1) {
                const u16* Kg1 = K + hbase + (long)(kt0 + 1) * 64 * 64;
                const u16* Vg1 = Vt + hbase + (long)(kt0 + 1) * 64;
#pragma unroll
                for (int i = 0; i < 2; ++i) {
                    kr[i] = *(const s16x8*)&Kg1[srow[i] * 64 + scol8[i]];
                    vr[i] = *(const s16x8*)&Vg1[(long)srow[i] * 2048 + scol8[i]];
                }
            }
        }
        __syncthreads();

#pragma unroll 1
        for (int j = 0; j < ntl; ++j) {
            int kt = kt0 + j;
            int cur = j & 1;
            if (j + 1 < ntl) {
#pragma unroll
                for (int i = 0; i < 2; ++i) {
                    *(s16x8*)&Ks[cur ^ 1][srow[i] * PAD + scol8[i]]  = kr[i];
                    *(s16x8*)&Vts[cur ^ 1][srow[i] * PAD + scol8[i]] = vr[i];
                }
            }
            if (j + 2 < ntl) {
                const u16* Kg = K + hbase + (long)(kt + 2) * 64 * 64;
                const u16* Vg = Vt + hbase + (long)(kt + 2) * 64;
#pragma unroll
                for (int i = 0; i < 2; ++i) {
                    kr[i] = *(const s16x8*)&Kg[srow[i] * 64 + scol8[i]];
                    vr[i] = *(const s16x8*)&Vg[(long)srow[i] * 2048 + scol8[i]];
                }
            }

#pragma unroll
            for (int k2 = 0; k2 < 2; ++k2) {
                int kbase = kt * 64 + k2 * 32;
                if (kbase <= q0w + 31) {    // else fully masked for this wave
                    f32x16 s = {};
                    __builtin_amdgcn_s_setprio(1);
#pragma unroll
                    for (int c = 0; c < 4; ++c) {
                        s16x8 ak = *(const s16x8*)&Ks[cur][(k2 * 32 + l31) * PAD + c * 16 + hi * 8];
                        s = mfma32(ak, bq[c], s);
                    }
                    __builtin_amdgcn_s_setprio(0);

                    // causal mask in RAW domain (diag-straddling tiles only)
                    if (kbase + 31 > q0w) {
                        int d = qv - (kbase + 4 * hi);  // pat > d -> masked
#pragma unroll
                        for (int r = 0; r < 16; ++r) {
                            int pat = (r & 3) + 8 * (r >> 2);
                            if (pat > d) s[r] = -3.0e38f;
                        }
                    }

                    // raw max tree, then single scale mul
                    float t8[8], t4[4];
#pragma unroll
                    for (int r = 0; r < 8; ++r) t8[r] = fmaxf(s[r], s[r + 8]);
#pragma unroll
                    for (int r = 0; r < 4; ++r) t4[r] = fmaxf(t8[r], t8[r + 4]);
                    float pm = fmaxf(fmaxf(t4[0], t4[2]), fmaxf(t4[1], t4[3]));
                    pm *= SC2;
                    pm = fmaxf(pm, __shfl_xor(pm, 32));

                    int allok = __all(pm - mrow <= THR);
                    float ef = 1.f;
                    if (!allok) {
                        float mn = fmaxf(mrow, pm);
                        ef = exp2f(mrow - mn);
                        mrow = mn;
                    }
                    // fused scale+shift exp2
#pragma unroll
                    for (int r = 0; r < 16; ++r) s[r] = exp2f(fmaf(s[r], SC2, -mrow));
                    float a8[8], a4[4];
#pragma unroll
                    for (int r = 0; r < 8; ++r) a8[r] = s[r] + s[r + 8];
#pragma unroll
                    for (int r = 0; r < 4; ++r) a4[r] = a8[r] + a8[r + 4];
                    float rsum = (a4[0] + a4[1]) + (a4[2] + a4[3]);
                    rsum += __shfl_xor(rsum, 32);

                    if (!allok) {
                        lrow = lrow * ef + rsum;
                        xbuf[w][l31] = ef;
#pragma unroll
                        for (int rr = 0; rr < 4; ++rr) {
                            f32x4 efv = *(const f32x4*)&xbuf[w][rr * 8 + hi * 4];
#pragma unroll
                            for (int j2 = 0; j2 < 4; ++j2) {
                                o0[rr * 4 + j2] *= efv[j2];
                                o1[rr * 4 + j2] *= efv[j2];
                            }
                        }
                    } else {
                        lrow += rsum;
                    }

                    unsigned c0 = pk2(s[0],  s[1]),  c1 = pk2(s[2],  s[3]);
                    unsigned c2 = pk2(s[4],  s[5]),  c3 = pk2(s[6],  s[7]);
                    unsigned c4 = pk2(s[8],  s[9]),  c5 = pk2(s[10], s[11]);
                    unsigned c6 = pk2(s[12], s[13]), c7 = pk2(s[14], s[15]);
                    unsigned x0 = __shfl_xor((int)c0, 32), x1 = __shfl_xor((int)c1, 32);
                    unsigned x2 = __shfl_xor((int)c2, 32), x3 = __shfl_xor((int)c3, 32);
                    unsigned x4 = __shfl_xor((int)c4, 32), x5 = __shfl_xor((int)c5, 32);
                    unsigned x6 = __shfl_xor((int)c6, 32), x7 = __shfl_xor((int)c7, 32);
                    u32x4 w0 = { h ? x2 : c0, h ? x3 : c1, h ? c2 : x0, h ? c3 : x1 };
                    u32x4 w1 = { h ? x6 : c4, h ? x7 : c5, h ? c6 : x4, h ? c7 : x5 };
                    s16x8 pa0 = __builtin_bit_cast(s16x8, w0);
                    s16x8 pa1 = __builtin_bit_cast(s16x8, w1);

                    __builtin_amdgcn_s_setprio(1);
#pragma unroll
                    for (int ks = 0; ks < 2; ++ks) {
                        s16x8 pa = ks ? pa1 : pa0;
                        s16x8 bv0 = *(const s16x8*)&Vts[cur][(l31) * PAD + k2 * 32 + ks * 16 + hi * 8];
                        s16x8 bv1 = *(const s16x8*)&Vts[cur][(32 + l31) * PAD + k2 * 32 + ks * 16 + hi * 8];
                        o0 = mfma32(pa, bv0, o0);
                        o1 = mfma32(pa, bv1, o1);
                    }
                    __builtin_amdgcn_s_setprio(0);
                }
            }
            __syncthreads();
        }

        // ---- partial epilogue: unnormalized O', m, l ----
        u16* Ops = ph ? Op1 : Op0;
#pragma unroll
        for (int r = 0; r < 16; ++r) {
            int t = q0w + ((r & 3) + 8 * (r >> 2)) + 4 * hi;
            long ro = (rb + t) * 64;
            Ops[ro + l31]      = f2bf(o0[r]);
            Ops[ro + 32 + l31] = f2bf(o1[r]);
        }
        if (hi == 0) {
            long mrow_i = rb + q0w + l31;
            ML[ph * 262144 + mrow_i]          = mrow;
            ML[ph * 262144 + 131072 + mrow_i] = lrow;
        }
        __syncthreads();   // protect LDS before next phase's prologue writes
    }
}

// ---------------------------------------------------------------------------
// Split-K combine: O = (w1*O1' + w2*O2') / (w1*l1 + w2*l2), w_s = 2^(m_s-mm).
// ---------------------------------------------------------------------------
__global__ __launch_bounds__(256) void attn_combine(
    const u16* __restrict__ Op0, const u16* __restrict__ Op1,
    const float* __restrict__ ML, u16* __restrict__ O)
{
    int tid = threadIdx.x;
    long row = (long)blockIdx.x * 16 + (tid >> 4);      // 0..131071
    int d0 = (tid & 15) * 4;
    float m1 = ML[row],          l1 = ML[131072 + row];
    float m2 = ML[262144 + row], l2 = ML[393216 + row];
    float mm = fmaxf(m1, m2);
    float w1 = exp2f(m1 - mm), w2 = exp2f(m2 - mm);
    float inv = 1.0f / (w1 * l1 + w2 * l2);
    ushort4 a = *(const ushort4*)&Op0[row * 64 + d0];
    ushort4 b = *(const ushort4*)&Op1[row * 64 + d0];
    ushort4 o;
    o.x = f2bf((w1 * bf2f(a.x) + w2 * bf2f(b.x)) * inv);
    o.y = f2bf((w1 * bf2f(a.y) + w2 * bf2f(b.y)) * inv);
    o.z = f2bf((w1 * bf2f(a.z) + w2 * bf2f(b.z)) * inv);
    o.w = f2bf((w1 * bf2f(a.w) + w2 * bf2f(b.w)) * inv);
    int bb = (int)(row >> 15), hh2 = (int)((row >> 11) & 15), t = (int)(row & 2047);
    *(ushort4*)&O[((long)(bb * 2048 + t)) * 1024 + hh2 * 64 + d0] = o;
}

// ---------------------------------------------------------------------------
extern "C" void kernel_launch(void* const* d_in, const int* in_sizes, int n_in,
                              void* d_out, int out_size, void* d_ws, size_t ws_size,
                              hipStream_t stream)
{
    const float* x      = (const float*)d_in[0];
    const float* wq     = (const float*)d_in[1];
    const float* wk     = (const float*)d_in[2];
    const float* wv     = (const float*)d_in[3];
    const float* w_proj = (const float*)d_in[4];
    const float* b_proj = (const float*)d_in[5];
    const float* w1     = (const float*)d_in[6];
    const float* b1     = (const float*)d_in[7];
    const float* w2     = (const float*)d_in[8];
    const float* b2     = (const float*)d_in[9];
    const float* ln1_g  = (const float*)d_in[10];
    const float* ln1_b  = (const float*)d_in[11];
    const float* ln2_g  = (const float*)d_in[12];
    const float* ln2_b  = (const float*)d_in[13];

    char* ws = (char*)d_ws;
    u16*   WQKVt = (u16*)(ws + 0);           // 3072x1024 bf16
    u16*   WPt   = (u16*)(ws + 6291456);     // 1024x1024
    u16*   W1t   = (u16*)(ws + 8388608);     // 4096x1024
    u16*   W2t   = (u16*)(ws + 16777216);    // 1024x4096
    u16*   H     = (u16*)(ws + 25165824);    // 8192x1024 (h, then h2)
    float* ML    = (float*)(ws + 25165824);  // overlaps H (dead during attn)
    u16*   Qb    = (u16*)(ws + 41943040);    // [B,H,T,D]
    u16*   Kb    = (u16*)(ws + 58720256);    // [B,H,T,D]
    u16*   Vb    = (u16*)(ws + 75497472);    // [B,H,D,T]  (transposed)
    u16*   Ob    = (u16*)(ws + 92274688);    // [B,T,C]
    u16*   FF    = (u16*)(ws + 41943040);    // 8192x4096, overlaps Q..O
    float* X1    = (float*)(ws + 109051904); // 8192x1024 fp32
    u16*   Op0   = (u16*)(ws + 109051904);   // split partials overlap X1
    u16*   Op1   = (u16*)(ws + 109051904 + 16777216);
    float* out   = (float*)d_out;

    transpose_cvt<<<dim3(16, 1, 16), 256, 0, stream>>>(wq, WQKVt,           1024, 64, 65536, 65536);
    transpose_cvt<<<dim3(16, 1, 16), 256, 0, stream>>>(wk, WQKVt + 1048576, 1024, 64, 65536, 65536);
    transpose_cvt<<<dim3(16, 1, 16), 256, 0, stream>>>(wv, WQKVt + 2097152, 1024, 64, 65536, 65536);
    transpose_cvt<<<dim3(16, 16, 1), 256, 0, stream>>>(w_proj, WPt, 1024, 1024, 0, 0);
    transpose_cvt<<<dim3(16, 64, 1), 256, 0, stream>>>(w1, W1t, 1024, 4096, 0, 0);
    transpose_cvt<<<dim3(64, 16, 1), 256, 0, stream>>>(w2, W2t, 4096, 1024, 0, 0);

    ln_bf16<<<8192, 256, 0, stream>>>(x, ln1_g, ln1_b, H);

    gemm_big<0><<<dim3(32, 24), 512, 0, stream>>>(H, WQKVt, 8192, 3072, 1024,
        nullptr, nullptr, nullptr, nullptr, Qb, Kb, Vb);

    attn_split<<<dim3(16, 16, 4), 256, 0, stream>>>(Qb, Kb, Vb, Op0, Op1, ML);
    attn_combine<<<8192, 256, 0, stream>>>(Op0, Op1, ML, Ob);

    gemm_bt<1><<<dim3(64, 8), 256, 0, stream>>>(Ob, WPt, 8192, 1024, 1024,
        X1, nullptr, b_proj, x, nullptr, nullptr, nullptr);

    ln_bf16<<<8192, 256, 0, stream>>>(X1, ln2_g, ln2_b, H);

    gemm_big<2><<<dim3(32, 32), 512, 0, stream>>>(H, W1t, 8192, 4096, 1024,
        nullptr, FF, b1, nullptr, nullptr, nullptr, nullptr);

    gemm_big<1><<<dim3(32, 8), 512, 0, stream>>>(FF, W2t, 8192, 1024, 4096,
        out, nullptr, b2, X1, nullptr, nullptr, nullptr);
}

// Round 19
// 401.234 us; speedup vs baseline: 1.1699x; 1.1015x over previous
//
#include <hip/hip_runtime.h>

// ---------------------------------------------------------------------------
// TransformerBlock on MI355X (gfx950), bf16 MFMA internal compute.
// B=4 T=2048 C=1024 H=16 D=64 FF=4096. All fp32 I/O; bf16 internally.
//
// R18: FF2 reverted to gemm_bt (R17's 256-tile FF2 = 1 block/CU latency
// regime: 134us, falsified).  GEMM stack = R13-exact (best total 411.2):
// gemm_big QKV/FF1, gemm_bt proj/FF2.  Attention R11-exact.
// NEW: all 6 weight transposes fused into ONE 3072-block dispatch
// (kills 5 underfilled launches, ~30us -> ~10us).
// ---------------------------------------------------------------------------

#define DEVI __device__ __forceinline__

typedef float  f32x4  __attribute__((ext_vector_type(4)));
typedef float  f32x16 __attribute__((ext_vector_type(16)));
typedef __bf16 bf16x8 __attribute__((ext_vector_type(8)));
typedef short  s16x8  __attribute__((ext_vector_type(8)));
typedef unsigned int u32x4 __attribute__((ext_vector_type(4)));
typedef unsigned short u16;

DEVI u16 f2bf(float f) {            // native RNE fp32->bf16
    return __builtin_bit_cast(u16, (__bf16)f);
}

DEVI float bf2f(u16 u) {
    unsigned v = (unsigned)u << 16;
    return __builtin_bit_cast(float, v);
}

DEVI unsigned pk2(float lo, float hi2) {    // {bf16(lo), bf16(hi2)} dword
    return (unsigned)f2bf(lo) | ((unsigned)f2bf(hi2) << 16);
}

DEVI void gload_lds16(const void* g, void* l) {
    __builtin_amdgcn_global_load_lds(
        (__attribute__((address_space(1))) void*)(g),
        (__attribute__((address_space(3))) void*)(l), 16, 0, 0);
}

DEVI f32x4 mfma16(s16x8 a, s16x8 b, f32x4 c) {
    return __builtin_amdgcn_mfma_f32_16x16x32_bf16(
        __builtin_bit_cast(bf16x8, a), __builtin_bit_cast(bf16x8, b), c, 0, 0, 0);
}

DEVI f32x16 mfma32(s16x8 a, s16x8 b, f32x16 c) {
    return __builtin_amdgcn_mfma_f32_32x32x16_bf16(
        __builtin_bit_cast(bf16x8, a), __builtin_bit_cast(bf16x8, b), c, 0, 0, 0);
}

// ---------------------------------------------------------------------------
// Fused weight transpose + fp32->bf16.  One dispatch, 3072 blocks.
// Tasks: 0/1/2 = wq/wk/wv (per-head 1024x64 -> 64x1024 chunks of WQKVt),
//        3 = w_proj (1024^2), 4 = w1 (1024x4096 -> 4096x1024),
//        5 = w2 (4096x1024 -> 1024x4096).
// ---------------------------------------------------------------------------
__global__ __launch_bounds__(256) void transpose_all(
    const float* __restrict__ wq, const float* __restrict__ wk,
    const float* __restrict__ wv, const float* __restrict__ w_proj,
    const float* __restrict__ w1, const float* __restrict__ w2,
    u16* __restrict__ WQKVt, u16* __restrict__ WPt,
    u16* __restrict__ W1t, u16* __restrict__ W2t)
{
    __shared__ float t[64][65];
    int b = blockIdx.x;
    const float* src; u16* dst; int srcN, dstK, k0, n0;
    if (b < 768) {                       // qkv: 3 x (16 k-tiles x 16 heads)
        int task = b >> 8, rel = b & 255;
        int kx = rel & 15, head = rel >> 4;
        src = (task == 0 ? wq : (task == 1 ? wk : wv)) + (long)head * 65536;
        dst = WQKVt + (long)task * 1048576 + (long)head * 65536;
        srcN = 64; dstK = 1024; k0 = kx * 64; n0 = 0;
    } else if (b < 1024) {               // w_proj: 16 x 16
        int rel = b - 768, kx = rel & 15, ny = rel >> 4;
        src = w_proj; dst = WPt; srcN = 1024; dstK = 1024;
        k0 = kx * 64; n0 = ny * 64;
    } else if (b < 2048) {               // w1: 16 k-tiles x 64 n-tiles
        int rel = b - 1024, kx = rel & 15, ny = rel >> 4;
        src = w1; dst = W1t; srcN = 4096; dstK = 1024;
        k0 = kx * 64; n0 = ny * 64;
    } else {                             // w2: 64 k-tiles x 16 n-tiles
        int rel = b - 2048, kx = rel & 63, ny = rel >> 6;
        src = w2; dst = W2t; srcN = 1024; dstK = 4096;
        k0 = kx * 64; n0 = ny * 64;
    }
    int tx = threadIdx.x & 63, ty = threadIdx.x >> 6;
#pragma unroll
    for (int i = 0; i < 16; ++i) {
        int r = ty * 16 + i;
        t[r][tx] = src[(long)(k0 + r) * srcN + n0 + tx];
    }
    __syncthreads();
#pragma unroll
    for (int i = 0; i < 16; ++i) {
        int r = ty * 16 + i;
        dst[(long)(n0 + r) * dstK + k0 + tx] = f2bf(t[tx][r]);
    }
}

// ---------------------------------------------------------------------------
// LayerNorm row (C=1024) -> bf16.  1 row / block, 256 threads, float4 loads.
// ---------------------------------------------------------------------------
__global__ __launch_bounds__(256) void ln_bf16(
    const float* __restrict__ x, const float* __restrict__ g,
    const float* __restrict__ b, u16* __restrict__ out)
{
    int row = blockIdx.x, tid = threadIdx.x;
    const float4 v = ((const float4*)(x + (long)row * 1024))[tid];
    float s = v.x + v.y + v.z + v.w;
    float q = v.x * v.x + v.y * v.y + v.z * v.z + v.w * v.w;
#pragma unroll
    for (int m = 1; m < 64; m <<= 1) { s += __shfl_xor(s, m); q += __shfl_xor(q, m); }
    __shared__ float red[8];
    int lane = tid & 63, w = tid >> 6;
    if (lane == 0) { red[w] = s; red[w + 4] = q; }
    __syncthreads();
    s = red[0] + red[1] + red[2] + red[3];
    q = red[4] + red[5] + red[6] + red[7];
    float mu  = s * (1.0f / 1024.0f);
    float var = q * (1.0f / 1024.0f) - mu * mu;
    float rs  = rsqrtf(var + 1e-5f);
    float4 gv = ((const float4*)g)[tid];
    float4 bv = ((const float4*)b)[tid];
    ushort4 o;
    o.x = f2bf((v.x - mu) * rs * gv.x + bv.x);
    o.y = f2bf((v.y - mu) * rs * gv.y + bv.y);
    o.z = f2bf((v.z - mu) * rs * gv.z + bv.z);
    o.w = f2bf((v.w - mu) * rs * gv.w + bv.w);
    ((ushort4*)(out + (long)row * 1024))[tid] = o;
}

// ---------------------------------------------------------------------------
// gemm_big: C[M,N] = A[M,K] * Bt[N,K]^T.  256x128 tile, BK=32, 512 thr
// (8 waves 4Mx2N).  Chunk-swizzled LDS (row&3).  24KB LDS, 4 blocks/CU.
// EPI: 0 = QKV scatter (V transposed), 2 = relu(+bias) -> bf16.
// ---------------------------------------------------------------------------
template <int EPI>
__global__ __launch_bounds__(512, 4) void gemm_big(
    const u16* __restrict__ A, const u16* __restrict__ Bt,
    int M, int N, int K,
    u16* __restrict__ outB, const float* __restrict__ bias,
    u16* __restrict__ qd, u16* __restrict__ kd, u16* __restrict__ vd)
{
    __shared__ alignas(16) u16 As[256 * 32];
    __shared__ alignas(16) u16 Bs[128 * 32];
    int tid = threadIdx.x;
    int lane = tid & 63, w = tid >> 6;
    int wm = w >> 1, wn = w & 1;
    int l15 = lane & 15, l4 = lane >> 4;
    long m0 = (long)blockIdx.x * 256, n0 = (long)blockIdx.y * 128;
    const u16* Ag = A + m0 * K;
    const u16* Bg = Bt + n0 * K;
    int srow_l = lane >> 2;                        // 0..15
    int schunk = ((lane & 3) ^ (srow_l & 3)) * 8;  // inverse-swizzled source
    int rchunk = (l4 ^ (l15 & 3)) * 8;             // swizzled read chunk

    f32x4 acc[4][4] = {};

    for (int kt = 0; kt < K; kt += 32) {
        gload_lds16(Ag + (long)(w * 32 + srow_l) * K + kt + schunk,
                    &As[(w * 32) * 32]);
        gload_lds16(Ag + (long)(w * 32 + 16 + srow_l) * K + kt + schunk,
                    &As[(w * 32 + 16) * 32]);
        gload_lds16(Bg + (long)(w * 16 + srow_l) * K + kt + schunk,
                    &Bs[(w * 16) * 32]);
        __syncthreads();
        s16x8 a[4], b[4];
#pragma unroll
        for (int m = 0; m < 4; ++m)
            a[m] = *(const s16x8*)&As[(wm * 64 + m * 16 + l15) * 32 + rchunk];
#pragma unroll
        for (int n = 0; n < 4; ++n)
            b[n] = *(const s16x8*)&Bs[(wn * 64 + n * 16 + l15) * 32 + rchunk];
#pragma unroll
        for (int m = 0; m < 4; ++m)
#pragma unroll
            for (int n = 0; n < 4; ++n)
                acc[m][n] = mfma16(a[m], b[n], acc[m][n]);
        __syncthreads();
    }

    long mbase = m0 + wm * 64;
    long nbase = n0 + wn * 64;
#pragma unroll
    for (int m = 0; m < 4; ++m)
#pragma unroll
        for (int n = 0; n < 4; ++n)
#pragma unroll
            for (int r = 0; r < 4; ++r) {
                long row = mbase + m * 16 + l4 * 4 + r;
                long col = nbase + n * 16 + l15;
                float val = acc[m][n][r];
                if constexpr (EPI == 0) {
                    int c = (int)col;
                    int which = c >> 10, hh = (c >> 6) & 15, dd = c & 63;
                    int bb = (int)(row >> 11), tt = (int)(row & 2047);
                    if (which == 2) {
                        vd[((long)(bb * 16 + hh) * 64 + dd) * 2048 + tt] = f2bf(val);
                    } else {
                        u16* dst = which == 0 ? qd : kd;
                        dst[((long)(bb * 16 + hh) * 2048 + tt) * 64 + dd] = f2bf(val);
                    }
                } else {
                    float t2 = val + bias[col];
                    outB[row * N + col] = f2bf(t2 > 0.f ? t2 : 0.f);
                }
            }
}

// ---------------------------------------------------------------------------
// GEMM 128x128 (m97 structure, R13-exact) for proj / FF2.  Chunk-swizzled.
// EPI 1 = +bias+resid -> fp32.
// ---------------------------------------------------------------------------
template <int EPI>
__global__ __launch_bounds__(256, 3) void gemm_bt(
    const u16* __restrict__ A, const u16* __restrict__ Bt,
    int M, int N, int K,
    float* __restrict__ outF, u16* __restrict__ outB,
    const float* __restrict__ bias, const float* __restrict__ resid,
    u16* __restrict__ qd, u16* __restrict__ kd, u16* __restrict__ vd)
{
    __shared__ alignas(16) u16 As[128 * 32];
    __shared__ alignas(16) u16 Bs[128 * 32];
    int tid = threadIdx.x;
    int lane = tid & 63, w = tid >> 6;
    int wm = w & 1, wn = w >> 1;
    int l15 = lane & 15, l4 = lane >> 4;
    long m0 = (long)blockIdx.x * 128, n0 = (long)blockIdx.y * 128;
    const u16* Ag = A + m0 * K;
    const u16* Bg = Bt + n0 * K;
    int scol = ((lane & 3) ^ ((lane >> 2) & 3)) * 8;   // inverse-swizzled src
    int srow0 = (w * 2 + 0) * 16 + (lane >> 2);
    int srow1 = (w * 2 + 1) * 16 + (lane >> 2);
    int rchunk = (l4 ^ (l15 & 3)) * 8;                 // swizzled read chunk

    f32x4 acc[4][4] = {};

    for (int kt = 0; kt < K; kt += 32) {
        gload_lds16(Ag + (long)srow0 * K + kt + scol, &As[(w * 2 + 0) * 512]);
        gload_lds16(Ag + (long)srow1 * K + kt + scol, &As[(w * 2 + 1) * 512]);
        gload_lds16(Bg + (long)srow0 * K + kt + scol, &Bs[(w * 2 + 0) * 512]);
        gload_lds16(Bg + (long)srow1 * K + kt + scol, &Bs[(w * 2 + 1) * 512]);
        __syncthreads();
        s16x8 a[4], b[4];
#pragma unroll
        for (int m = 0; m < 4; ++m)
            a[m] = *(const s16x8*)&As[(wm * 64 + m * 16 + l15) * 32 + rchunk];
#pragma unroll
        for (int n = 0; n < 4; ++n)
            b[n] = *(const s16x8*)&Bs[(wn * 64 + n * 16 + l15) * 32 + rchunk];
#pragma unroll
        for (int m = 0; m < 4; ++m)
#pragma unroll
            for (int n = 0; n < 4; ++n)
                acc[m][n] = mfma16(a[m], b[n], acc[m][n]);
        __syncthreads();
    }

    long mbase = m0 + wm * 64;
    long nbase = n0 + wn * 64;
#pragma unroll
    for (int m = 0; m < 4; ++m)
#pragma unroll
        for (int n = 0; n < 4; ++n)
#pragma unroll
            for (int r = 0; r < 4; ++r) {
                long row = mbase + m * 16 + l4 * 4 + r;
                long col = nbase + n * 16 + l15;
                float val = acc[m][n][r];
                if constexpr (EPI == 1) {
                    outF[row * N + col] = val + bias[col] + resid[row * N + col];
                }
            }
}

// ---------------------------------------------------------------------------
// Causal flash attention, split-K partials (R11-exact).
// Block p = (qt=p, s=0) then (qt=15-p, s=1); 17 tiles/block, 4 blocks/CU.
// ---------------------------------------------------------------------------
__global__ __launch_bounds__(256, 4) void attn_split(
    const u16* __restrict__ Q, const u16* __restrict__ K,
    const u16* __restrict__ Vt,
    u16* __restrict__ Op0, u16* __restrict__ Op1, float* __restrict__ ML)
{
    constexpr int PAD = 72;
    constexpr float SC2 = 0.125f * 1.44269504088896f;   // scale * log2(e)
    constexpr float THR = 11.5416f;                     // 8 * log2(e)
    __shared__ alignas(16) u16 Ks[2][64 * PAD];
    __shared__ alignas(16) u16 Vts[2][64 * PAD];
    __shared__ alignas(16) float xbuf[4][32];           // per-wave bounce
    int tid = threadIdx.x, lane = tid & 63, w = tid >> 6;
    int l31 = lane & 31, hi = lane >> 5;
    bool h = (hi != 0);
    int p = blockIdx.x, hh = blockIdx.y, bb = blockIdx.z;
    const long hbase = ((long)(bb * 16 + hh)) * 2048 * 64;
    const long rb = ((long)(bb * 16 + hh)) * 2048;      // partial row base

    int srow[2], scol8[2];
#pragma unroll
    for (int i = 0; i < 2; ++i) {
        int c = tid + 256 * i;
        srow[i] = c >> 3;
        scol8[i] = (c & 7) * 8;
    }

#pragma unroll 1
    for (int ph = 0; ph < 2; ++ph) {
        int qt  = ph == 0 ? p : 15 - p;
        int kt0 = ph == 0 ? 0 : (qt + 1);
        int kt1 = qt + 1 + ph * (qt + 1);   // ph0: qt+1, ph1: 2qt+2
        int ntl = kt1 - kt0;
        int q0w = qt * 128 + w * 32;
        int qv = q0w + l31;                 // this lane's q row

        s16x8 bq[4];
#pragma unroll
        for (int c = 0; c < 4; ++c)
            bq[c] = *(const s16x8*)&Q[hbase + (long)(q0w + l31) * 64 + c * 16 + hi * 8];

        f32x16 o0 = {}, o1 = {};            // O'[q=crow][d=l31 | 32+l31]
        float mrow = -1e30f, lrow = 0.f;

        s16x8 kr[2], vr[2];
        {
            const u16* Kg = K + hbase + (long)kt0 * 64 * 64;
            const u16* Vg = Vt + hbase + (long)kt0 * 64;
#pragma unroll
            for (int i = 0; i < 2; ++i) {
                s16x8 k0 = *(const s16x8*)&Kg[srow[i] * 64 + scol8[i]];
                s16x8 v0 = *(const s16x8*)&Vg[(long)srow[i] * 2048 + scol8[i]];
                *(s16x8*)&Ks[0][srow[i] * PAD + scol8[i]]  = k0;
                *(s16x8*)&Vts[0][srow[i] * PAD + scol8[i]] = v0;
            }
            if (ntl > 1) {
                const u16* Kg1 = K + hbase + (long)(kt0 + 1) * 64 * 64;
                const u16* Vg1 = Vt + hbase + (long)(kt0 + 1) * 64;
#pragma unroll
                for (int i = 0; i < 2; ++i) {
                    kr[i] = *(const s16x8*)&Kg1[srow[i] * 64 + scol8[i]];
                    vr[i] = *(const s16x8*)&Vg1[(long)srow[i] * 2048 + scol8[i]];
                }
            }
        }
        __syncthreads();

#pragma unroll 1
        for (int j = 0; j < ntl; ++j) {
            int kt = kt0 + j;
            int cur = j & 1;
            if (j + 1 < ntl) {
#pragma unroll
                for (int i = 0; i < 2; ++i) {
                    *(s16x8*)&Ks[cur ^ 1][srow[i] * PAD + scol8[i]]  = kr[i];
                    *(s16x8*)&Vts[cur ^ 1][srow[i] * PAD + scol8[i]] = vr[i];
                }
            }
            if (j + 2 < ntl) {
                const u16* Kg = K + hbase + (long)(kt + 2) * 64 * 64;
                const u16* Vg = Vt + hbase + (long)(kt + 2) * 64;
#pragma unroll
                for (int i = 0; i < 2; ++i) {
                    kr[i] = *(const s16x8*)&Kg[srow[i] * 64 + scol8[i]];
                    vr[i] = *(const s16x8*)&Vg[(long)srow[i] * 2048 + scol8[i]];
                }
            }

#pragma unroll
            for (int k2 = 0; k2 < 2; ++k2) {
                int kbase = kt * 64 + k2 * 32;
                if (kbase <= q0w + 31) {    // else fully masked for this wave
                    f32x16 s = {};
                    __builtin_amdgcn_s_setprio(1);
#pragma unroll
                    for (int c = 0; c < 4; ++c) {
                        s16x8 ak = *(const s16x8*)&Ks[cur][(k2 * 32 + l31) * PAD + c * 16 + hi * 8];
                        s = mfma32(ak, bq[c], s);
                    }
                    __builtin_amdgcn_s_setprio(0);

                    // causal mask in RAW domain (diag-straddling tiles only)
                    if (kbase + 31 > q0w) {
                        int d = qv - (kbase + 4 * hi);  // pat > d -> masked
#pragma unroll
                        for (int r = 0; r < 16; ++r) {
                            int pat = (r & 3) + 8 * (r >> 2);
                            if (pat > d) s[r] = -3.0e38f;
                        }
                    }

                    // raw max tree, then single scale mul
                    float t8[8], t4[4];
#pragma unroll
                    for (int r = 0; r < 8; ++r) t8[r] = fmaxf(s[r], s[r + 8]);
#pragma unroll
                    for (int r = 0; r < 4; ++r) t4[r] = fmaxf(t8[r], t8[r + 4]);
                    float pm = fmaxf(fmaxf(t4[0], t4[2]), fmaxf(t4[1], t4[3]));
                    pm *= SC2;
                    pm = fmaxf(pm, __shfl_xor(pm, 32));

                    int allok = __all(pm - mrow <= THR);
                    float ef = 1.f;
                    if (!allok) {
                        float mn = fmaxf(mrow, pm);
                        ef = exp2f(mrow - mn);
                        mrow = mn;
                    }
                    // fused scale+shift exp2
#pragma unroll
                    for (int r = 0; r < 16; ++r) s[r] = exp2f(fmaf(s[r], SC2, -mrow));
                    float a8[8], a4[4];
#pragma unroll
                    for (int r = 0; r < 8; ++r) a8[r] = s[r] + s[r + 8];
#pragma unroll
                    for (int r = 0; r < 4; ++r) a4[r] = a8[r] + a8[r + 4];
                    float rsum = (a4[0] + a4[1]) + (a4[2] + a4[3]);
                    rsum += __shfl_xor(rsum, 32);

                    if (!allok) {
                        lrow = lrow * ef + rsum;
                        xbuf[w][l31] = ef;
#pragma unroll
                        for (int rr = 0; rr < 4; ++rr) {
                            f32x4 efv = *(const f32x4*)&xbuf[w][rr * 8 + hi * 4];
#pragma unroll
                            for (int j2 = 0; j2 < 4; ++j2) {
                                o0[rr * 4 + j2] *= efv[j2];
                                o1[rr * 4 + j2] *= efv[j2];
                            }
                        }
                    } else {
                        lrow += rsum;
                    }

                    unsigned c0 = pk2(s[0],  s[1]),  c1 = pk2(s[2],  s[3]);
                    unsigned c2 = pk2(s[4],  s[5]),  c3 = pk2(s[6],  s[7]);
                    unsigned c4 = pk2(s[8],  s[9]),  c5 = pk2(s[10], s[11]);
                    unsigned c6 = pk2(s[12], s[13]), c7 = pk2(s[14], s[15]);
                    unsigned x0 = __shfl_xor((int)c0, 32), x1 = __shfl_xor((int)c1, 32);
                    unsigned x2 = __shfl_xor((int)c2, 32), x3 = __shfl_xor((int)c3, 32);
                    unsigned x4 = __shfl_xor((int)c4, 32), x5 = __shfl_xor((int)c5, 32);
                    unsigned x6 = __shfl_xor((int)c6, 32), x7 = __shfl_xor((int)c7, 32);
                    u32x4 w0 = { h ? x2 : c0, h ? x3 : c1, h ? c2 : x0, h ? c3 : x1 };
                    u32x4 w1 = { h ? x6 : c4, h ? x7 : c5, h ? c6 : x4, h ? c7 : x5 };
                    s16x8 pa0 = __builtin_bit_cast(s16x8, w0);
                    s16x8 pa1 = __builtin_bit_cast(s16x8, w1);

                    __builtin_amdgcn_s_setprio(1);
#pragma unroll
                    for (int ks = 0; ks < 2; ++ks) {
                        s16x8 pa = ks ? pa1 : pa0;
                        s16x8 bv0 = *(const s16x8*)&Vts[cur][(l31) * PAD + k2 * 32 + ks * 16 + hi * 8];
                        s16x8 bv1 = *(const s16x8*)&Vts[cur][(32 + l31) * PAD + k2 * 32 + ks * 16 + hi * 8];
                        o0 = mfma32(pa, bv0, o0);
                        o1 = mfma32(pa, bv1, o1);
                    }
                    __builtin_amdgcn_s_setprio(0);
                }
            }
            __syncthreads();
        }

        // ---- partial epilogue: unnormalized O', m, l ----
        u16* Ops = ph ? Op1 : Op0;
#pragma unroll
        for (int r = 0; r < 16; ++r) {
            int t = q0w + ((r & 3) + 8 * (r >> 2)) + 4 * hi;
            long ro = (rb + t) * 64;
            Ops[ro + l31]      = f2bf(o0[r]);
            Ops[ro + 32 + l31] = f2bf(o1[r]);
        }
        if (hi == 0) {
            long mrow_i = rb + q0w + l31;
            ML[ph * 262144 + mrow_i]          = mrow;
            ML[ph * 262144 + 131072 + mrow_i] = lrow;
        }
        __syncthreads();   // protect LDS before next phase's prologue writes
    }
}

// ---------------------------------------------------------------------------
// Split-K combine: O = (w1*O1' + w2*O2') / (w1*l1 + w2*l2), w_s = 2^(m_s-mm).
// ---------------------------------------------------------------------------
__global__ __launch_bounds__(256) void attn_combine(
    const u16* __restrict__ Op0, const u16* __restrict__ Op1,
    const float* __restrict__ ML, u16* __restrict__ O)
{
    int tid = threadIdx.x;
    long row = (long)blockIdx.x * 16 + (tid >> 4);      // 0..131071
    int d0 = (tid & 15) * 4;
    float m1 = ML[row],          l1 = ML[131072 + row];
    float m2 = ML[262144 + row], l2 = ML[393216 + row];
    float mm = fmaxf(m1, m2);
    float w1 = exp2f(m1 - mm), w2 = exp2f(m2 - mm);
    float inv = 1.0f / (w1 * l1 + w2 * l2);
    ushort4 a = *(const ushort4*)&Op0[row * 64 + d0];
    ushort4 b = *(const ushort4*)&Op1[row * 64 + d0];
    ushort4 o;
    o.x = f2bf((w1 * bf2f(a.x) + w2 * bf2f(b.x)) * inv);
    o.y = f2bf((w1 * bf2f(a.y) + w2 * bf2f(b.y)) * inv);
    o.z = f2bf((w1 * bf2f(a.z) + w2 * bf2f(b.z)) * inv);
    o.w = f2bf((w1 * bf2f(a.w) + w2 * bf2f(b.w)) * inv);
    int bb = (int)(row >> 15), hh2 = (int)((row >> 11) & 15), t = (int)(row & 2047);
    *(ushort4*)&O[((long)(bb * 2048 + t)) * 1024 + hh2 * 64 + d0] = o;
}

// ---------------------------------------------------------------------------
extern "C" void kernel_launch(void* const* d_in, const int* in_sizes, int n_in,
                              void* d_out, int out_size, void* d_ws, size_t ws_size,
                              hipStream_t stream)
{
    const float* x      = (const float*)d_in[0];
    const float* wq     = (const float*)d_in[1];
    const float* wk     = (const float*)d_in[2];
    const float* wv     = (const float*)d_in[3];
    const float* w_proj = (const float*)d_in[4];
    const float* b_proj = (const float*)d_in[5];
    const float* w1     = (const float*)d_in[6];
    const float* b1     = (const float*)d_in[7];
    const float* w2     = (const float*)d_in[8];
    const float* b2     = (const float*)d_in[9];
    const float* ln1_g  = (const float*)d_in[10];
    const float* ln1_b  = (const float*)d_in[11];
    const float* ln2_g  = (const float*)d_in[12];
    const float* ln2_b  = (const float*)d_in[13];

    char* ws = (char*)d_ws;
    u16*   WQKVt = (u16*)(ws + 0);           // 3072x1024 bf16
    u16*   WPt   = (u16*)(ws + 6291456);     // 1024x1024
    u16*   W1t   = (u16*)(ws + 8388608);     // 4096x1024
    u16*   W2t   = (u16*)(ws + 16777216);    // 1024x4096
    u16*   H     = (u16*)(ws + 25165824);    // 8192x1024 (h, then h2)
    float* ML    = (float*)(ws + 25165824);  // overlaps H (dead during attn)
    u16*   Qb    = (u16*)(ws + 41943040);    // [B,H,T,D]
    u16*   Kb    = (u16*)(ws + 58720256);    // [B,H,T,D]
    u16*   Vb    = (u16*)(ws + 75497472);    // [B,H,D,T]  (transposed)
    u16*   Ob    = (u16*)(ws + 92274688);    // [B,T,C]
    u16*   FF    = (u16*)(ws + 41943040);    // 8192x4096, overlaps Q..O
    float* X1    = (float*)(ws + 109051904); // 8192x1024 fp32
    u16*   Op0   = (u16*)(ws + 109051904);   // split partials overlap X1
    u16*   Op1   = (u16*)(ws + 109051904 + 16777216);
    float* out   = (float*)d_out;

    transpose_all<<<3072, 256, 0, stream>>>(wq, wk, wv, w_proj, w1, w2,
                                            WQKVt, WPt, W1t, W2t);

    ln_bf16<<<8192, 256, 0, stream>>>(x, ln1_g, ln1_b, H);

    gemm_big<0><<<dim3(32, 24), 512, 0, stream>>>(H, WQKVt, 8192, 3072, 1024,
        nullptr, nullptr, Qb, Kb, Vb);

    attn_split<<<dim3(16, 16, 4), 256, 0, stream>>>(Qb, Kb, Vb, Op0, Op1, ML);
    attn_combine<<<8192, 256, 0, stream>>>(Op0, Op1, ML, Ob);

    gemm_bt<1><<<dim3(64, 8), 256, 0, stream>>>(Ob, WPt, 8192, 1024, 1024,
        X1, nullptr, b_proj, x, nullptr, nullptr, nullptr);

    ln_bf16<<<8192, 256, 0, stream>>>(X1, ln2_g, ln2_b, H);

    gemm_big<2><<<dim3(32, 32), 512, 0, stream>>>(H, W1t, 8192, 4096, 1024,
        FF, b1, nullptr, nullptr, nullptr);

    gemm_bt<1><<<dim3(64, 8), 256, 0, stream>>>(FF, W2t, 8192, 1024, 4096,
        out, nullptr, b2, X1, nullptr, nullptr, nullptr);
}

// Round 20
// 396.270 us; speedup vs baseline: 1.1846x; 1.0125x over previous
//
#include <hip/hip_runtime.h>

// ---------------------------------------------------------------------------
// TransformerBlock on MI355X (gfx950), bf16 MFMA internal compute.
// B=4 T=2048 C=1024 H=16 D=64 FF=4096. All fp32 I/O; bf16 internally.
//
// R19: R18-exact (best 401.2us) + fuse {6 weight transposes, LN1} into a
// single 11264-block prep dispatch (both independent, both strictly before
// the QKV GEMM) -- removes one serialized launch/drain boundary.
// GEMM stack at the m97-structure verified per-step rate (1.17-1.22us/step);
// deeper pipelining falsified twice; attention latency-bound at 4 blk/CU.
// ---------------------------------------------------------------------------

#define DEVI __device__ __forceinline__

typedef float  f32x4  __attribute__((ext_vector_type(4)));
typedef float  f32x16 __attribute__((ext_vector_type(16)));
typedef __bf16 bf16x8 __attribute__((ext_vector_type(8)));
typedef short  s16x8  __attribute__((ext_vector_type(8)));
typedef unsigned int u32x4 __attribute__((ext_vector_type(4)));
typedef unsigned short u16;

DEVI u16 f2bf(float f) {            // native RNE fp32->bf16
    return __builtin_bit_cast(u16, (__bf16)f);
}

DEVI float bf2f(u16 u) {
    unsigned v = (unsigned)u << 16;
    return __builtin_bit_cast(float, v);
}

DEVI unsigned pk2(float lo, float hi2) {    // {bf16(lo), bf16(hi2)} dword
    return (unsigned)f2bf(lo) | ((unsigned)f2bf(hi2) << 16);
}

DEVI void gload_lds16(const void* g, void* l) {
    __builtin_amdgcn_global_load_lds(
        (__attribute__((address_space(1))) void*)(g),
        (__attribute__((address_space(3))) void*)(l), 16, 0, 0);
}

DEVI f32x4 mfma16(s16x8 a, s16x8 b, f32x4 c) {
    return __builtin_amdgcn_mfma_f32_16x16x32_bf16(
        __builtin_bit_cast(bf16x8, a), __builtin_bit_cast(bf16x8, b), c, 0, 0, 0);
}

DEVI f32x16 mfma32(s16x8 a, s16x8 b, f32x16 c) {
    return __builtin_amdgcn_mfma_f32_32x32x16_bf16(
        __builtin_bit_cast(bf16x8, a), __builtin_bit_cast(bf16x8, b), c, 0, 0, 0);
}

// ---------------------------------------------------------------------------
// Fused prep: weight transposes (blocks 0..3071) + LN1 (blocks 3072..11263).
// Transpose tasks: 0/1/2 = wq/wk/wv per-head, 3 = w_proj, 4 = w1, 5 = w2.
// LN: 1 row (C=1024) per block.
// ---------------------------------------------------------------------------
__global__ __launch_bounds__(256) void prep_kernel(
    const float* __restrict__ wq, const float* __restrict__ wk,
    const float* __restrict__ wv, const float* __restrict__ w_proj,
    const float* __restrict__ w1, const float* __restrict__ w2,
    u16* __restrict__ WQKVt, u16* __restrict__ WPt,
    u16* __restrict__ W1t, u16* __restrict__ W2t,
    const float* __restrict__ x, const float* __restrict__ g,
    const float* __restrict__ bb, u16* __restrict__ H)
{
    __shared__ float t[64][65];
    __shared__ float red[8];
    int b = blockIdx.x;
    if (b >= 3072) {
        // ---- LN1 row ----
        int row = b - 3072, tid = threadIdx.x;
        const float4 v = ((const float4*)(x + (long)row * 1024))[tid];
        float s = v.x + v.y + v.z + v.w;
        float q = v.x * v.x + v.y * v.y + v.z * v.z + v.w * v.w;
#pragma unroll
        for (int m = 1; m < 64; m <<= 1) { s += __shfl_xor(s, m); q += __shfl_xor(q, m); }
        int lane = tid & 63, w = tid >> 6;
        if (lane == 0) { red[w] = s; red[w + 4] = q; }
        __syncthreads();
        s = red[0] + red[1] + red[2] + red[3];
        q = red[4] + red[5] + red[6] + red[7];
        float mu  = s * (1.0f / 1024.0f);
        float var = q * (1.0f / 1024.0f) - mu * mu;
        float rs  = rsqrtf(var + 1e-5f);
        float4 gv = ((const float4*)g)[tid];
        float4 bv = ((const float4*)bb)[tid];
        ushort4 o;
        o.x = f2bf((v.x - mu) * rs * gv.x + bv.x);
        o.y = f2bf((v.y - mu) * rs * gv.y + bv.y);
        o.z = f2bf((v.z - mu) * rs * gv.z + bv.z);
        o.w = f2bf((v.w - mu) * rs * gv.w + bv.w);
        ((ushort4*)(H + (long)row * 1024))[tid] = o;
        return;
    }
    // ---- transpose task ----
    const float* src; u16* dst; int srcN, dstK, k0, n0;
    if (b < 768) {                       // qkv: 3 x (16 k-tiles x 16 heads)
        int task = b >> 8, rel = b & 255;
        int kx = rel & 15, head = rel >> 4;
        src = (task == 0 ? wq : (task == 1 ? wk : wv)) + (long)head * 65536;
        dst = WQKVt + (long)task * 1048576 + (long)head * 65536;
        srcN = 64; dstK = 1024; k0 = kx * 64; n0 = 0;
    } else if (b < 1024) {               // w_proj: 16 x 16
        int rel = b - 768, kx = rel & 15, ny = rel >> 4;
        src = w_proj; dst = WPt; srcN = 1024; dstK = 1024;
        k0 = kx * 64; n0 = ny * 64;
    } else if (b < 2048) {               // w1: 16 k-tiles x 64 n-tiles
        int rel = b - 1024, kx = rel & 15, ny = rel >> 4;
        src = w1; dst = W1t; srcN = 4096; dstK = 1024;
        k0 = kx * 64; n0 = ny * 64;
    } else {                             // w2: 64 k-tiles x 16 n-tiles
        int rel = b - 2048, kx = rel & 63, ny = rel >> 6;
        src = w2; dst = W2t; srcN = 1024; dstK = 4096;
        k0 = kx * 64; n0 = ny * 64;
    }
    int tx = threadIdx.x & 63, ty = threadIdx.x >> 6;
#pragma unroll
    for (int i = 0; i < 16; ++i) {
        int r = ty * 16 + i;
        t[r][tx] = src[(long)(k0 + r) * srcN + n0 + tx];
    }
    __syncthreads();
#pragma unroll
    for (int i = 0; i < 16; ++i) {
        int r = ty * 16 + i;
        dst[(long)(n0 + r) * dstK + k0 + tx] = f2bf(t[tx][r]);
    }
}

// ---------------------------------------------------------------------------
// LayerNorm row (C=1024) -> bf16.  1 row / block, 256 threads (LN2).
// ---------------------------------------------------------------------------
__global__ __launch_bounds__(256) void ln_bf16(
    const float* __restrict__ x, const float* __restrict__ g,
    const float* __restrict__ b, u16* __restrict__ out)
{
    int row = blockIdx.x, tid = threadIdx.x;
    const float4 v = ((const float4*)(x + (long)row * 1024))[tid];
    float s = v.x + v.y + v.z + v.w;
    float q = v.x * v.x + v.y * v.y + v.z * v.z + v.w * v.w;
#pragma unroll
    for (int m = 1; m < 64; m <<= 1) { s += __shfl_xor(s, m); q += __shfl_xor(q, m); }
    __shared__ float red[8];
    int lane = tid & 63, w = tid >> 6;
    if (lane == 0) { red[w] = s; red[w + 4] = q; }
    __syncthreads();
    s = red[0] + red[1] + red[2] + red[3];
    q = red[4] + red[5] + red[6] + red[7];
    float mu  = s * (1.0f / 1024.0f);
    float var = q * (1.0f / 1024.0f) - mu * mu;
    float rs  = rsqrtf(var + 1e-5f);
    float4 gv = ((const float4*)g)[tid];
    float4 bv = ((const float4*)b)[tid];
    ushort4 o;
    o.x = f2bf((v.x - mu) * rs * gv.x + bv.x);
    o.y = f2bf((v.y - mu) * rs * gv.y + bv.y);
    o.z = f2bf((v.z - mu) * rs * gv.z + bv.z);
    o.w = f2bf((v.w - mu) * rs * gv.w + bv.w);
    ((ushort4*)(out + (long)row * 1024))[tid] = o;
}

// ---------------------------------------------------------------------------
// gemm_big: C[M,N] = A[M,K] * Bt[N,K]^T.  256x128 tile, BK=32, 512 thr
// (8 waves 4Mx2N).  Chunk-swizzled LDS (row&3).  24KB LDS, 4 blocks/CU.
// EPI: 0 = QKV scatter (V transposed), 2 = relu(+bias) -> bf16.
// ---------------------------------------------------------------------------
template <int EPI>
__global__ __launch_bounds__(512, 4) void gemm_big(
    const u16* __restrict__ A, const u16* __restrict__ Bt,
    int M, int N, int K,
    u16* __restrict__ outB, const float* __restrict__ bias,
    u16* __restrict__ qd, u16* __restrict__ kd, u16* __restrict__ vd)
{
    __shared__ alignas(16) u16 As[256 * 32];
    __shared__ alignas(16) u16 Bs[128 * 32];
    int tid = threadIdx.x;
    int lane = tid & 63, w = tid >> 6;
    int wm = w >> 1, wn = w & 1;
    int l15 = lane & 15, l4 = lane >> 4;
    long m0 = (long)blockIdx.x * 256, n0 = (long)blockIdx.y * 128;
    const u16* Ag = A + m0 * K;
    const u16* Bg = Bt + n0 * K;
    int srow_l = lane >> 2;                        // 0..15
    int schunk = ((lane & 3) ^ (srow_l & 3)) * 8;  // inverse-swizzled source
    int rchunk = (l4 ^ (l15 & 3)) * 8;             // swizzled read chunk

    f32x4 acc[4][4] = {};

    for (int kt = 0; kt < K; kt += 32) {
        gload_lds16(Ag + (long)(w * 32 + srow_l) * K + kt + schunk,
                    &As[(w * 32) * 32]);
        gload_lds16(Ag + (long)(w * 32 + 16 + srow_l) * K + kt + schunk,
                    &As[(w * 32 + 16) * 32]);
        gload_lds16(Bg + (long)(w * 16 + srow_l) * K + kt + schunk,
                    &Bs[(w * 16) * 32]);
        __syncthreads();
        s16x8 a[4], b[4];
#pragma unroll
        for (int m = 0; m < 4; ++m)
            a[m] = *(const s16x8*)&As[(wm * 64 + m * 16 + l15) * 32 + rchunk];
#pragma unroll
        for (int n = 0; n < 4; ++n)
            b[n] = *(const s16x8*)&Bs[(wn * 64 + n * 16 + l15) * 32 + rchunk];
#pragma unroll
        for (int m = 0; m < 4; ++m)
#pragma unroll
            for (int n = 0; n < 4; ++n)
                acc[m][n] = mfma16(a[m], b[n], acc[m][n]);
        __syncthreads();
    }

    long mbase = m0 + wm * 64;
    long nbase = n0 + wn * 64;
#pragma unroll
    for (int m = 0; m < 4; ++m)
#pragma unroll
        for (int n = 0; n < 4; ++n)
#pragma unroll
            for (int r = 0; r < 4; ++r) {
                long row = mbase + m * 16 + l4 * 4 + r;
                long col = nbase + n * 16 + l15;
                float val = acc[m][n][r];
                if constexpr (EPI == 0) {
                    int c = (int)col;
                    int which = c >> 10, hh = (c >> 6) & 15, dd = c & 63;
                    int bb = (int)(row >> 11), tt = (int)(row & 2047);
                    if (which == 2) {
                        vd[((long)(bb * 16 + hh) * 64 + dd) * 2048 + tt] = f2bf(val);
                    } else {
                        u16* dst = which == 0 ? qd : kd;
                        dst[((long)(bb * 16 + hh) * 2048 + tt) * 64 + dd] = f2bf(val);
                    }
                } else {
                    float t2 = val + bias[col];
                    outB[row * N + col] = f2bf(t2 > 0.f ? t2 : 0.f);
                }
            }
}

// ---------------------------------------------------------------------------
// GEMM 128x128 (m97 structure, R13-exact) for proj / FF2.  Chunk-swizzled.
// EPI 1 = +bias+resid -> fp32.
// ---------------------------------------------------------------------------
template <int EPI>
__global__ __launch_bounds__(256, 3) void gemm_bt(
    const u16* __restrict__ A, const u16* __restrict__ Bt,
    int M, int N, int K,
    float* __restrict__ outF, u16* __restrict__ outB,
    const float* __restrict__ bias, const float* __restrict__ resid,
    u16* __restrict__ qd, u16* __restrict__ kd, u16* __restrict__ vd)
{
    __shared__ alignas(16) u16 As[128 * 32];
    __shared__ alignas(16) u16 Bs[128 * 32];
    int tid = threadIdx.x;
    int lane = tid & 63, w = tid >> 6;
    int wm = w & 1, wn = w >> 1;
    int l15 = lane & 15, l4 = lane >> 4;
    long m0 = (long)blockIdx.x * 128, n0 = (long)blockIdx.y * 128;
    const u16* Ag = A + m0 * K;
    const u16* Bg = Bt + n0 * K;
    int scol = ((lane & 3) ^ ((lane >> 2) & 3)) * 8;   // inverse-swizzled src
    int srow0 = (w * 2 + 0) * 16 + (lane >> 2);
    int srow1 = (w * 2 + 1) * 16 + (lane >> 2);
    int rchunk = (l4 ^ (l15 & 3)) * 8;                 // swizzled read chunk

    f32x4 acc[4][4] = {};

    for (int kt = 0; kt < K; kt += 32) {
        gload_lds16(Ag + (long)srow0 * K + kt + scol, &As[(w * 2 + 0) * 512]);
        gload_lds16(Ag + (long)srow1 * K + kt + scol, &As[(w * 2 + 1) * 512]);
        gload_lds16(Bg + (long)srow0 * K + kt + scol, &Bs[(w * 2 + 0) * 512]);
        gload_lds16(Bg + (long)srow1 * K + kt + scol, &Bs[(w * 2 + 1) * 512]);
        __syncthreads();
        s16x8 a[4], b[4];
#pragma unroll
        for (int m = 0; m < 4; ++m)
            a[m] = *(const s16x8*)&As[(wm * 64 + m * 16 + l15) * 32 + rchunk];
#pragma unroll
        for (int n = 0; n < 4; ++n)
            b[n] = *(const s16x8*)&Bs[(wn * 64 + n * 16 + l15) * 32 + rchunk];
#pragma unroll
        for (int m = 0; m < 4; ++m)
#pragma unroll
            for (int n = 0; n < 4; ++n)
                acc[m][n] = mfma16(a[m], b[n], acc[m][n]);
        __syncthreads();
    }

    long mbase = m0 + wm * 64;
    long nbase = n0 + wn * 64;
#pragma unroll
    for (int m = 0; m < 4; ++m)
#pragma unroll
        for (int n = 0; n < 4; ++n)
#pragma unroll
            for (int r = 0; r < 4; ++r) {
                long row = mbase + m * 16 + l4 * 4 + r;
                long col = nbase + n * 16 + l15;
                float val = acc[m][n][r];
                if constexpr (EPI == 1) {
                    outF[row * N + col] = val + bias[col] + resid[row * N + col];
                }
            }
}

// ---------------------------------------------------------------------------
// Causal flash attention, split-K partials (R11-exact).
// Block p = (qt=p, s=0) then (qt=15-p, s=1); 17 tiles/block, 4 blocks/CU.
// ---------------------------------------------------------------------------
__global__ __launch_bounds__(256, 4) void attn_split(
    const u16* __restrict__ Q, const u16* __restrict__ K,
    const u16* __restrict__ Vt,
    u16* __restrict__ Op0, u16* __restrict__ Op1, float* __restrict__ ML)
{
    constexpr int PAD = 72;
    constexpr float SC2 = 0.125f * 1.44269504088896f;   // scale * log2(e)
    constexpr float THR = 11.5416f;                     // 8 * log2(e)
    __shared__ alignas(16) u16 Ks[2][64 * PAD];
    __shared__ alignas(16) u16 Vts[2][64 * PAD];
    __shared__ alignas(16) float xbuf[4][32];           // per-wave bounce
    int tid = threadIdx.x, lane = tid & 63, w = tid >> 6;
    int l31 = lane & 31, hi = lane >> 5;
    bool h = (hi != 0);
    int p = blockIdx.x, hh = blockIdx.y, bb = blockIdx.z;
    const long hbase = ((long)(bb * 16 + hh)) * 2048 * 64;
    const long rb = ((long)(bb * 16 + hh)) * 2048;      // partial row base

    int srow[2], scol8[2];
#pragma unroll
    for (int i = 0; i < 2; ++i) {
        int c = tid + 256 * i;
        srow[i] = c >> 3;
        scol8[i] = (c & 7) * 8;
    }

#pragma unroll 1
    for (int ph = 0; ph < 2; ++ph) {
        int qt  = ph == 0 ? p : 15 - p;
        int kt0 = ph == 0 ? 0 : (qt + 1);
        int kt1 = qt + 1 + ph * (qt + 1);   // ph0: qt+1, ph1: 2qt+2
        int ntl = kt1 - kt0;
        int q0w = qt * 128 + w * 32;
        int qv = q0w + l31;                 // this lane's q row

        s16x8 bq[4];
#pragma unroll
        for (int c = 0; c < 4; ++c)
            bq[c] = *(const s16x8*)&Q[hbase + (long)(q0w + l31) * 64 + c * 16 + hi * 8];

        f32x16 o0 = {}, o1 = {};            // O'[q=crow][d=l31 | 32+l31]
        float mrow = -1e30f, lrow = 0.f;

        s16x8 kr[2], vr[2];
        {
            const u16* Kg = K + hbase + (long)kt0 * 64 * 64;
            const u16* Vg = Vt + hbase + (long)kt0 * 64;
#pragma unroll
            for (int i = 0; i < 2; ++i) {
                s16x8 k0 = *(const s16x8*)&Kg[srow[i] * 64 + scol8[i]];
                s16x8 v0 = *(const s16x8*)&Vg[(long)srow[i] * 2048 + scol8[i]];
                *(s16x8*)&Ks[0][srow[i] * PAD + scol8[i]]  = k0;
                *(s16x8*)&Vts[0][srow[i] * PAD + scol8[i]] = v0;
            }
            if (ntl > 1) {
                const u16* Kg1 = K + hbase + (long)(kt0 + 1) * 64 * 64;
                const u16* Vg1 = Vt + hbase + (long)(kt0 + 1) * 64;
#pragma unroll
                for (int i = 0; i < 2; ++i) {
                    kr[i] = *(const s16x8*)&Kg1[srow[i] * 64 + scol8[i]];
                    vr[i] = *(const s16x8*)&Vg1[(long)srow[i] * 2048 + scol8[i]];
                }
            }
        }
        __syncthreads();

#pragma unroll 1
        for (int j = 0; j < ntl; ++j) {
            int kt = kt0 + j;
            int cur = j & 1;
            if (j + 1 < ntl) {
#pragma unroll
                for (int i = 0; i < 2; ++i) {
                    *(s16x8*)&Ks[cur ^ 1][srow[i] * PAD + scol8[i]]  = kr[i];
                    *(s16x8*)&Vts[cur ^ 1][srow[i] * PAD + scol8[i]] = vr[i];
                }
            }
            if (j + 2 < ntl) {
                const u16* Kg = K + hbase + (long)(kt + 2) * 64 * 64;
                const u16* Vg = Vt + hbase + (long)(kt + 2) * 64;
#pragma unroll
                for (int i = 0; i < 2; ++i) {
                    kr[i] = *(const s16x8*)&Kg[srow[i] * 64 + scol8[i]];
                    vr[i] = *(const s16x8*)&Vg[(long)srow[i] * 2048 + scol8[i]];
                }
            }

#pragma unroll
            for (int k2 = 0; k2 < 2; ++k2) {
                int kbase = kt * 64 + k2 * 32;
                if (kbase <= q0w + 31) {    // else fully masked for this wave
                    f32x16 s = {};
                    __builtin_amdgcn_s_setprio(1);
#pragma unroll
                    for (int c = 0; c < 4; ++c) {
                        s16x8 ak = *(const s16x8*)&Ks[cur][(k2 * 32 + l31) * PAD + c * 16 + hi * 8];
                        s = mfma32(ak, bq[c], s);
                    }
                    __builtin_amdgcn_s_setprio(0);

                    // causal mask in RAW domain (diag-straddling tiles only)
                    if (kbase + 31 > q0w) {
                        int d = qv - (kbase + 4 * hi);  // pat > d -> masked
#pragma unroll
                        for (int r = 0; r < 16; ++r) {
                            int pat = (r & 3) + 8 * (r >> 2);
                            if (pat > d) s[r] = -3.0e38f;
                        }
                    }

                    // raw max tree, then single scale mul
                    float t8[8], t4[4];
#pragma unroll
                    for (int r = 0; r < 8; ++r) t8[r] = fmaxf(s[r], s[r + 8]);
#pragma unroll
                    for (int r = 0; r < 4; ++r) t4[r] = fmaxf(t8[r], t8[r + 4]);
                    float pm = fmaxf(fmaxf(t4[0], t4[2]), fmaxf(t4[1], t4[3]));
                    pm *= SC2;
                    pm = fmaxf(pm, __shfl_xor(pm, 32));

                    int allok = __all(pm - mrow <= THR);
                    float ef = 1.f;
                    if (!allok) {
                        float mn = fmaxf(mrow, pm);
                        ef = exp2f(mrow - mn);
                        mrow = mn;
                    }
                    // fused scale+shift exp2
#pragma unroll
                    for (int r = 0; r < 16; ++r) s[r] = exp2f(fmaf(s[r], SC2, -mrow));
                    float a8[8], a4[4];
#pragma unroll
                    for (int r = 0; r < 8; ++r) a8[r] = s[r] + s[r + 8];
#pragma unroll
                    for (int r = 0; r < 4; ++r) a4[r] = a8[r] + a8[r + 4];
                    float rsum = (a4[0] + a4[1]) + (a4[2] + a4[3]);
                    rsum += __shfl_xor(rsum, 32);

                    if (!allok) {
                        lrow = lrow * ef + rsum;
                        xbuf[w][l31] = ef;
#pragma unroll
                        for (int rr = 0; rr < 4; ++rr) {
                            f32x4 efv = *(const f32x4*)&xbuf[w][rr * 8 + hi * 4];
#pragma unroll
                            for (int j2 = 0; j2 < 4; ++j2) {
                                o0[rr * 4 + j2] *= efv[j2];
                                o1[rr * 4 + j2] *= efv[j2];
                            }
                        }
                    } else {
                        lrow += rsum;
                    }

                    unsigned c0 = pk2(s[0],  s[1]),  c1 = pk2(s[2],  s[3]);
                    unsigned c2 = pk2(s[4],  s[5]),  c3 = pk2(s[6],  s[7]);
                    unsigned c4 = pk2(s[8],  s[9]),  c5 = pk2(s[10], s[11]);
                    unsigned c6 = pk2(s[12], s[13]), c7 = pk2(s[14], s[15]);
                    unsigned x0 = __shfl_xor((int)c0, 32), x1 = __shfl_xor((int)c1, 32);
                    unsigned x2 = __shfl_xor((int)c2, 32), x3 = __shfl_xor((int)c3, 32);
                    unsigned x4 = __shfl_xor((int)c4, 32), x5 = __shfl_xor((int)c5, 32);
                    unsigned x6 = __shfl_xor((int)c6, 32), x7 = __shfl_xor((int)c7, 32);
                    u32x4 w0 = { h ? x2 : c0, h ? x3 : c1, h ? c2 : x0, h ? c3 : x1 };
                    u32x4 w1 = { h ? x6 : c4, h ? x7 : c5, h ? c6 : x4, h ? c7 : x5 };
                    s16x8 pa0 = __builtin_bit_cast(s16x8, w0);
                    s16x8 pa1 = __builtin_bit_cast(s16x8, w1);

                    __builtin_amdgcn_s_setprio(1);
#pragma unroll
                    for (int ks = 0; ks < 2; ++ks) {
                        s16x8 pa = ks ? pa1 : pa0;
                        s16x8 bv0 = *(const s16x8*)&Vts[cur][(l31) * PAD + k2 * 32 + ks * 16 + hi * 8];
                        s16x8 bv1 = *(const s16x8*)&Vts[cur][(32 + l31) * PAD + k2 * 32 + ks * 16 + hi * 8];
                        o0 = mfma32(pa, bv0, o0);
                        o1 = mfma32(pa, bv1, o1);
                    }
                    __builtin_amdgcn_s_setprio(0);
                }
            }
            __syncthreads();
        }

        // ---- partial epilogue: unnormalized O', m, l ----
        u16* Ops = ph ? Op1 : Op0;
#pragma unroll
        for (int r = 0; r < 16; ++r) {
            int t = q0w + ((r & 3) + 8 * (r >> 2)) + 4 * hi;
            long ro = (rb + t) * 64;
            Ops[ro + l31]      = f2bf(o0[r]);
            Ops[ro + 32 + l31] = f2bf(o1[r]);
        }
        if (hi == 0) {
            long mrow_i = rb + q0w + l31;
            ML[ph * 262144 + mrow_i]          = mrow;
            ML[ph * 262144 + 131072 + mrow_i] = lrow;
        }
        __syncthreads();   // protect LDS before next phase's prologue writes
    }
}

// ---------------------------------------------------------------------------
// Split-K combine: O = (w1*O1' + w2*O2') / (w1*l1 + w2*l2), w_s = 2^(m_s-mm).
// ---------------------------------------------------------------------------
__global__ __launch_bounds__(256) void attn_combine(
    const u16* __restrict__ Op0, const u16* __restrict__ Op1,
    const float* __restrict__ ML, u16* __restrict__ O)
{
    int tid = threadIdx.x;
    long row = (long)blockIdx.x * 16 + (tid >> 4);      // 0..131071
    int d0 = (tid & 15) * 4;
    float m1 = ML[row],          l1 = ML[131072 + row];
    float m2 = ML[262144 + row], l2 = ML[393216 + row];
    float mm = fmaxf(m1, m2);
    float w1 = exp2f(m1 - mm), w2 = exp2f(m2 - mm);
    float inv = 1.0f / (w1 * l1 + w2 * l2);
    ushort4 a = *(const ushort4*)&Op0[row * 64 + d0];
    ushort4 b = *(const ushort4*)&Op1[row * 64 + d0];
    ushort4 o;
    o.x = f2bf((w1 * bf2f(a.x) + w2 * bf2f(b.x)) * inv);
    o.y = f2bf((w1 * bf2f(a.y) + w2 * bf2f(b.y)) * inv);
    o.z = f2bf((w1 * bf2f(a.z) + w2 * bf2f(b.z)) * inv);
    o.w = f2bf((w1 * bf2f(a.w) + w2 * bf2f(b.w)) * inv);
    int bb = (int)(row >> 15), hh2 = (int)((row >> 11) & 15), t = (int)(row & 2047);
    *(ushort4*)&O[((long)(bb * 2048 + t)) * 1024 + hh2 * 64 + d0] = o;
}

// ---------------------------------------------------------------------------
extern "C" void kernel_launch(void* const* d_in, const int* in_sizes, int n_in,
                              void* d_out, int out_size, void* d_ws, size_t ws_size,
                              hipStream_t stream)
{
    const float* x      = (const float*)d_in[0];
    const float* wq     = (const float*)d_in[1];
    const float* wk     = (const float*)d_in[2];
    const float* wv     = (const float*)d_in[3];
    const float* w_proj = (const float*)d_in[4];
    const float* b_proj = (const float*)d_in[5];
    const float* w1     = (const float*)d_in[6];
    const float* b1     = (const float*)d_in[7];
    const float* w2     = (const float*)d_in[8];
    const float* b2     = (const float*)d_in[9];
    const float* ln1_g  = (const float*)d_in[10];
    const float* ln1_b  = (const float*)d_in[11];
    const float* ln2_g  = (const float*)d_in[12];
    const float* ln2_b  = (const float*)d_in[13];

    char* ws = (char*)d_ws;
    u16*   WQKVt = (u16*)(ws + 0);           // 3072x1024 bf16
    u16*   WPt   = (u16*)(ws + 6291456);     // 1024x1024
    u16*   W1t   = (u16*)(ws + 8388608);     // 4096x1024
    u16*   W2t   = (u16*)(ws + 16777216);    // 1024x4096
    u16*   H     = (u16*)(ws + 25165824);    // 8192x1024 (h, then h2)
    float* ML    = (float*)(ws + 25165824);  // overlaps H (dead during attn)
    u16*   Qb    = (u16*)(ws + 41943040);    // [B,H,T,D]
    u16*   Kb    = (u16*)(ws + 58720256);    // [B,H,T,D]
    u16*   Vb    = (u16*)(ws + 75497472);    // [B,H,D,T]  (transposed)
    u16*   Ob    = (u16*)(ws + 92274688);    // [B,T,C]
    u16*   FF    = (u16*)(ws + 41943040);    // 8192x4096, overlaps Q..O
    float* X1    = (float*)(ws + 109051904); // 8192x1024 fp32
    u16*   Op0   = (u16*)(ws + 109051904);   // split partials overlap X1
    u16*   Op1   = (u16*)(ws + 109051904 + 16777216);
    float* out   = (float*)d_out;

    prep_kernel<<<11264, 256, 0, stream>>>(wq, wk, wv, w_proj, w1, w2,
                                           WQKVt, WPt, W1t, W2t,
                                           x, ln1_g, ln1_b, H);

    gemm_big<0><<<dim3(32, 24), 512, 0, stream>>>(H, WQKVt, 8192, 3072, 1024,
        nullptr, nullptr, Qb, Kb, Vb);

    attn_split<<<dim3(16, 16, 4), 256, 0, stream>>>(Qb, Kb, Vb, Op0, Op1, ML);
    attn_combine<<<8192, 256, 0, stream>>>(Op0, Op1, ML, Ob);

    gemm_bt<1><<<dim3(64, 8), 256, 0, stream>>>(Ob, WPt, 8192, 1024, 1024,
        X1, nullptr, b_proj, x, nullptr, nullptr, nullptr);

    ln_bf16<<<8192, 256, 0, stream>>>(X1, ln2_g, ln2_b, H);

    gemm_big<2><<<dim3(32, 32), 512, 0, stream>>>(H, W1t, 8192, 4096, 1024,
        FF, b1, nullptr, nullptr, nullptr);

    gemm_bt<1><<<dim3(64, 8), 256, 0, stream>>>(FF, W2t, 8192, 1024, 4096,
        out, nullptr, b2, X1, nullptr, nullptr, nullptr);
}